// Round 7
// baseline (337.314 us; speedup 1.0000x reference)
//
#include <hip/hip_runtime.h>
#include <hip/hip_bf16.h>

// Problem: N=4096, Dx=512, Dz=64.
// out[0]=total, out[1]=rank_loss, out[2]=pairdist_loss (f32).
//
// Pipeline:
//   1. prep: nx[i]=sum x[i]^2 (f32), nz likewise; cast x,z to bf16.
//   2. gram_dist (merged x+z, bf16 MFMA, global_load_lds 16B staging):
//      d = sqrt(max(n_i + n_j - 2*(A A^T)_ij, 0)), stored u16
//      q0 = min(floor(d*qscale), 65535), qscale 1024 (x) / 2048 (z).
//      Also reduces global off-diag min / global max of q per matrix
//      (4 u32 atomics) for the rank kernel's bin normalization.
//   3. rank kernel: 512 threads, TWO rows per block (half-block per row).
//      Global-normalized 11-bit bins; one ds_add_rtn pass counts AND yields
//      intra-bin offsets; dual scan (2 waves per histogram); final plain
//      ds_read pass: rank = scanned_base + offset; |rx-rz| inline.
//      ~5 barriers serve 2 rows (r6: 5 barriers per row) — attacks the
//      exposed latency chain diagnosed from occupancy 13% / VALUBusy 23%.
//   4. finalize: 3 scalars.

#define N 4096
#define DX 512
#define DZ 64
#define NBIN 2048          // 11-bit global-normalized bins
#define NWRD (NBIN / 2)    // u16-packed pairs -> 1024 u32 words per hist

typedef __attribute__((ext_vector_type(8))) short short8;
typedef __attribute__((ext_vector_type(4))) float float4v;

// stats word layout (u32 index into qstats):
//   [0..1] rank_acc (u64)  [2..3] pd_acc (double)
//   [4] maxx [5] maxz      [6] minx [7] minz
#define ST_MAX 4
#define ST_MIN 6

// ---------------- async 16B global -> LDS ----------------
__device__ __forceinline__ void async16(const void* g, void* l) {
  __builtin_amdgcn_global_load_lds(
      (const __attribute__((address_space(1))) unsigned int*)(g),
      (__attribute__((address_space(3))) unsigned int*)(l), 16, 0, 0);
}

// ---------------- prep: norms + bf16 casts ----------------
__global__ __launch_bounds__(256) void prep_kernel(
    const float* __restrict__ x, const float* __restrict__ z,
    __hip_bfloat16* __restrict__ xb, __hip_bfloat16* __restrict__ zb,
    float* __restrict__ nx, float* __restrict__ nz) {
  int row = blockIdx.x;
  int tid = threadIdx.x;
  __shared__ float red[256];

  float sx = 0.f;
  for (int c = tid; c < DX; c += 256) {
    float v = x[(size_t)row * DX + c];
    xb[(size_t)row * DX + c] = __float2bfloat16(v);
    sx += v * v;
  }
  red[tid] = sx;
  __syncthreads();
  for (int s = 128; s > 0; s >>= 1) {
    if (tid < s) red[tid] += red[tid + s];
    __syncthreads();
  }
  if (tid == 0) nx[row] = red[0];
  __syncthreads();

  float sz = 0.f;
  if (tid < DZ) {
    float v = z[(size_t)row * DZ + tid];
    zb[(size_t)row * DZ + tid] = __float2bfloat16(v);
    sz = v * v;
  }
  red[tid] = sz;
  __syncthreads();
  for (int s = 128; s > 0; s >>= 1) {
    if (tid < s) red[tid] += red[tid + s];
    __syncthreads();
  }
  if (tid == 0) nz[row] = red[0];
}

// ------- merged bf16 MFMA Gram (x & z) + quantized-distance epilogue -----
#define TILE 128
#define BK 32

__global__ __launch_bounds__(256) void gram_dist_kernel(
    const __hip_bfloat16* __restrict__ xb, const __hip_bfloat16* __restrict__ zb,
    const float* __restrict__ nx, const float* __restrict__ nz,
    unsigned short* __restrict__ qx16, unsigned short* __restrict__ qz16,
    unsigned* __restrict__ qstats) {
  __shared__ short As[TILE * BK];  // 8 KB, row-major [128][32]
  __shared__ short Bs[TILE * BK];

  int isz = (int)(blockIdx.x >> 10);  // 0: x-matrix, 1: z-matrix
  int flat = (int)(blockIdx.x & 1023);
  int by = flat >> 5, bx = flat & 31;

  const __hip_bfloat16* Abf = isz ? zb : xb;
  const float* norms = isz ? nz : nx;
  unsigned short* distq = isz ? qz16 : qx16;
  const int K = isz ? DZ : DX;
  const float qscale = isz ? 2048.0f : 1024.0f;

  int tid = threadIdx.x;
  int wave = tid >> 6, lane = tid & 63;
  int wr = wave >> 1, wc = wave & 1;
  int quad = lane >> 4, l15 = lane & 15;

  int rowBase = by * TILE;
  int colBase = bx * TILE;

  float4v acc[4][4];
#pragma unroll
  for (int mi = 0; mi < 4; ++mi)
#pragma unroll
    for (int ni = 0; ni < 4; ++ni) {
      float4v zv = {0.f, 0.f, 0.f, 0.f};
      acc[mi][ni] = zv;
    }

  const char* Ab = (const char*)Abf;
  const size_t rb = (size_t)K * 2;  // row bytes
  int chunk0 = wave * 2, chunk1 = wave * 2 + 1;
  int rl = lane >> 2;        // row within a 16-row chunk (4 lanes/row)
  int cl = (lane & 3) * 16;  // byte col within 64B row

  for (int kc = 0; kc < K; kc += BK) {
    const char* base = Ab + (size_t)kc * 2 + cl;
    async16(base + (size_t)(rowBase + chunk0 * 16 + rl) * rb,
            &As[chunk0 * 512]);
    async16(base + (size_t)(rowBase + chunk1 * 16 + rl) * rb,
            &As[chunk1 * 512]);
    async16(base + (size_t)(colBase + chunk0 * 16 + rl) * rb,
            &Bs[chunk0 * 512]);
    async16(base + (size_t)(colBase + chunk1 * 16 + rl) * rb,
            &Bs[chunk1 * 512]);
    __syncthreads();

    short8 a[4], b[4];
#pragma unroll
    for (int mi = 0; mi < 4; ++mi)
      a[mi] = *(const short8*)(&As[(wr * 64 + mi * 16 + l15) * BK + quad * 8]);
#pragma unroll
    for (int ni = 0; ni < 4; ++ni)
      b[ni] = *(const short8*)(&Bs[(wc * 64 + ni * 16 + l15) * BK + quad * 8]);
#pragma unroll
    for (int mi = 0; mi < 4; ++mi)
#pragma unroll
      for (int ni = 0; ni < 4; ++ni)
        acc[mi][ni] = __builtin_amdgcn_mfma_f32_16x16x32_bf16(
            a[mi], b[ni], acc[mi][ni], 0, 0, 0);
    __syncthreads();
  }

  unsigned mn = 0xFFFFu, mx = 0u;
#pragma unroll
  for (int mi = 0; mi < 4; ++mi) {
#pragma unroll
    for (int ni = 0; ni < 4; ++ni) {
      int col = colBase + wc * 64 + ni * 16 + l15;
      float ncol = norms[col];
#pragma unroll
      for (int r = 0; r < 4; ++r) {
        int row = rowBase + wr * 64 + mi * 16 + quad * 4 + r;
        float sq = norms[row] + ncol - 2.0f * acc[mi][ni][r];
        float d = sq > 0.f ? sqrtf(sq) : 0.f;
        if (row == col) d = 0.f;
        unsigned q = (unsigned)(d * qscale);
        q = q > 65535u ? 65535u : q;
        distq[(size_t)row * N + col] = (unsigned short)q;
        mx = max(mx, q);
        mn = min(mn, (row == col) ? 0xFFFFu : q);
      }
    }
  }
  // wave reduce + device atomics for global off-diag min / max
#pragma unroll
  for (int d = 32; d; d >>= 1) {
    mn = min(mn, (unsigned)__shfl_xor((int)mn, d, 64));
    mx = max(mx, (unsigned)__shfl_xor((int)mx, d, 64));
  }
  if (lane == 0) {
    atomicMax(&qstats[ST_MAX + isz], mx);
    atomicMin(&qstats[ST_MIN + isz], mn);
  }
}

// ---------------- counting-based per-row ranks (2 rows / block) ----------
// Word-index swizzle (bijective per 32-word block): sequential per-thread
// scan accesses become low-way bank aliasing instead of 16/32-way.
__device__ __forceinline__ int hsw(int w) { return w ^ ((w >> 5) & 31); }

__global__ __launch_bounds__(512) void rank_kernel(
    const unsigned short* __restrict__ qx,
    const unsigned short* __restrict__ qz,
    const unsigned* __restrict__ qstats,
    unsigned long long* __restrict__ rank_acc, double* __restrict__ pd_acc) {
  __shared__ unsigned hists[4 * NWRD];  // [rowsel][X,Z] -> 16 KB
  __shared__ unsigned xch[64];

  int t = threadIdx.x;
  int tt = t & 255, rowsel = t >> 8;
  int row = (int)blockIdx.x * 2 + rowsel;
  int lane = t & 63, wv = t >> 6;

  unsigned* hX = hists + rowsel * 2 * NWRD;
  unsigned* hZ = hX + NWRD;

  const uint4* px = (const uint4*)(qx + (size_t)row * N);
  const uint4* pz = (const uint4*)(qz + (size_t)row * N);

  // ---- load my 16 x and 16 z values (row depends on half-block) ----
  uint4 xa = px[tt * 2], xb4 = px[tt * 2 + 1];
  uint4 za = pz[tt * 2], zb4 = pz[tt * 2 + 1];
  unsigned xw[8] = {xa.x, xa.y, xa.z, xa.w, xb4.x, xb4.y, xb4.z, xb4.w};
  unsigned zw[8] = {za.x, za.y, za.z, za.w, zb4.x, zb4.y, zb4.z, zb4.w};

  // zero all four hists (independent of loads)
#pragma unroll
  for (int i = 0; i < 8; ++i) hists[t + 512 * i] = 0u;

  // global bin transform (uniform scalar loads)
  float lox = (float)(int)qstats[ST_MIN + 0];
  float scx = (float)(NBIN - 1) /
              (float)(int)max(1u, qstats[ST_MAX + 0] - qstats[ST_MIN + 0]);
  float loz = (float)(int)qstats[ST_MIN + 1];
  float scz = (float)(NBIN - 1) /
              (float)(int)max(1u, qstats[ST_MAX + 1] - qstats[ST_MIN + 1]);

  // ---- pairdist partial (no barrier needed yet) ----
  float pd = 0.f;
#pragma unroll
  for (int c = 0; c < 16; ++c) {
    unsigned qxv = (xw[c >> 1] >> ((c & 1) * 16)) & 0xFFFFu;
    unsigned qzv = (zw[c >> 1] >> ((c & 1) * 16)) & 0xFFFFu;
    // dz-dx = ((qz+.5)/2048 - (qx+.5)/1024) = (qz - 2*qx - 0.5)/2048
    float tv = (float)(int)qzv - 2.0f * (float)(int)qxv - 0.5f;
    pd += tv * tv;
  }
  __syncthreads();  // hist zeroing complete

  // ---- single atomic pass: count AND capture intra-bin offset ----
  unsigned oxp[8], ozp[8];
#pragma unroll
  for (int c = 0; c < 16; ++c) {
    unsigned qxv = (xw[c >> 1] >> ((c & 1) * 16)) & 0xFFFFu;
    unsigned qzv = (zw[c >> 1] >> ((c & 1) * 16)) & 0xFFFFu;
    unsigned bx = (unsigned)(int)fminf(
        fmaxf(((float)(int)qxv - lox) * scx, 0.0f), (float)(NBIN - 1));
    unsigned bz = (unsigned)(int)fminf(
        fmaxf(((float)(int)qzv - loz) * scz, 0.0f), (float)(NBIN - 1));
    unsigned shx = (bx & 1) * 16, shz = (bz & 1) * 16;
    unsigned ox =
        (atomicAdd(&hX[hsw((int)(bx >> 1))], 1u << shx) >> shx) & 0xFFFFu;
    unsigned oz =
        (atomicAdd(&hZ[hsw((int)(bz >> 1))], 1u << shz) >> shz) & 0xFFFFu;
    if (c & 1) {
      oxp[c >> 1] |= ox << 16;
      ozp[c >> 1] |= oz << 16;
    } else {
      oxp[c >> 1] = ox;
      ozp[c >> 1] = oz;
    }
  }
  __syncthreads();

  // ---- scans: 8 waves, 2 waves per histogram ----
  {
    unsigned* h = hists + (wv >> 1) * NWRD;
    int t2 = t & 127;
    int wb = t2 * 8;
    unsigned run = 0;
#pragma unroll
    for (int c = 0; c < 8; ++c) {
      int w = hsw(wb + c);
      unsigned v = h[w];
      unsigned lo = v & 0xFFFFu;
      h[w] = run | ((run + lo) << 16);
      run += lo + (v >> 16);
    }
    unsigned incl = run;
#pragma unroll
    for (int d = 1; d < 64; d <<= 1) {
      unsigned o = (unsigned)__shfl_up((int)incl, d, 64);
      if (lane >= d) incl += o;
    }
    if (lane == 63) xch[16 + wv] = incl;
    __syncthreads();
    unsigned base = incl - run;              // exclusive within my wave
    if (wv & 1) base += xch[16 + (wv - 1)];  // add lower wave of my hist
    unsigned add = base * 0x10001u;
#pragma unroll
    for (int c = 0; c < 8; ++c) h[hsw(wb + c)] += add;
  }
  __syncthreads();

  // ---- final pass: plain ds_read of scanned bases; |rx-rz| inline ----
  int rsum = 0;
#pragma unroll
  for (int c = 0; c < 16; ++c) {
    unsigned qxv = (xw[c >> 1] >> ((c & 1) * 16)) & 0xFFFFu;
    unsigned qzv = (zw[c >> 1] >> ((c & 1) * 16)) & 0xFFFFu;
    unsigned bx = (unsigned)(int)fminf(
        fmaxf(((float)(int)qxv - lox) * scx, 0.0f), (float)(NBIN - 1));
    unsigned bz = (unsigned)(int)fminf(
        fmaxf(((float)(int)qzv - loz) * scz, 0.0f), (float)(NBIN - 1));
    unsigned shx = (bx & 1) * 16, shz = (bz & 1) * 16;
    unsigned basex = (hX[hsw((int)(bx >> 1))] >> shx) & 0xFFFFu;
    unsigned basez = (hZ[hsw((int)(bz >> 1))] >> shz) & 0xFFFFu;
    int rx = (int)(basex + ((oxp[c >> 1] >> ((c & 1) * 16)) & 0xFFFFu));
    int rz = (int)(basez + ((ozp[c >> 1] >> ((c & 1) * 16)) & 0xFFFFu));
    int d = rx - rz;
    rsum += d < 0 ? -d : d;
  }

  // ---- block reduce (8 waves) + global atomics ----
#pragma unroll
  for (int d = 32; d; d >>= 1) {
    rsum += __shfl_xor(rsum, d, 64);
    pd += __shfl_xor(pd, d, 64);
  }
  if (lane == 0) {
    xch[wv] = (unsigned)rsum;
    ((float*)xch)[32 + wv] = pd;
  }
  __syncthreads();
  if (t == 0) {
    unsigned long long rtot = 0;
    float ptot = 0.f;
#pragma unroll
    for (int w = 0; w < 8; ++w) {
      rtot += (unsigned long long)xch[w];
      ptot += ((float*)xch)[32 + w];
    }
    atomicAdd(rank_acc, rtot);
    atomicAdd(pd_acc, (double)ptot);
  }
}

// ---------------- finalize ----------------
__global__ void finalize_kernel(const unsigned long long* __restrict__ racc,
                                const double* __restrict__ pacc,
                                float* __restrict__ out) {
  double inv = 1.0 / ((double)N * (double)N);
  double rank_loss = (double)(*racc) * inv / 32.0;  // K = 32
  double pd = (*pacc) * inv / (2048.0 * 2048.0);    // undo q scaling
  out[0] = (float)(rank_loss + 0.5 * pd);
  out[1] = (float)rank_loss;
  out[2] = (float)pd;
}

// ---------------- launch ----------------
extern "C" void kernel_launch(void* const* d_in, const int* in_sizes, int n_in,
                              void* d_out, int out_size, void* d_ws,
                              size_t ws_size, hipStream_t stream) {
  (void)in_sizes; (void)n_in; (void)out_size; (void)ws_size;
  const float* x = (const float*)d_in[0];
  const float* z = (const float*)d_in[1];
  float* out = (float*)d_out;

  char* w = (char*)d_ws;
  unsigned short* qx16 = (unsigned short*)(w);             // 32 MB
  unsigned short* qz16 = (unsigned short*)(w + 33554432);  // 32 MB
  __hip_bfloat16* xb = (__hip_bfloat16*)(w + 67108864);    // 4 MB
  __hip_bfloat16* zb = (__hip_bfloat16*)(w + 71303168);    // 0.5 MB
  float* nx = (float*)(w + 71827456);
  float* nz = (float*)(w + 71843840);
  unsigned* qstats = (unsigned*)(w + 71860224);
  unsigned long long* rank_acc = (unsigned long long*)(w + 71860224);
  double* pd_acc = (double*)(w + 71860224 + 8);

  // [0..23] = rank_acc, pd_acc, maxx, maxz -> 0 ; [24..31] = minx,minz -> ~0
  hipMemsetAsync(w + 71860224, 0, 24, stream);
  hipMemsetAsync(w + 71860224 + 24, 0xFF, 8, stream);

  prep_kernel<<<N, 256, 0, stream>>>(x, z, xb, zb, nx, nz);

  gram_dist_kernel<<<2048, 256, 0, stream>>>(xb, zb, nx, nz, qx16, qz16,
                                             qstats);

  rank_kernel<<<N / 2, 512, 0, stream>>>(qx16, qz16, qstats, rank_acc, pd_acc);

  finalize_kernel<<<1, 1, 0, stream>>>(rank_acc, pd_acc, out);
}

// Round 8
// 197.348 us; speedup vs baseline: 1.7092x; 1.7092x over previous
//
#include <hip/hip_runtime.h>
#include <hip/hip_bf16.h>

// Problem: N=4096, Dx=512, Dz=64.
// out[0]=total, out[1]=rank_loss, out[2]=pairdist_loss (f32).
//
// Pipeline:
//   1. prep: nx[i]=sum x[i]^2 (f32), nz likewise; cast x,z to bf16.
//   2. gram_dist x2 (bf16 MFMA, global_load_lds staging, SYMMETRIC):
//      only upper-triangular 128x128 tiles computed (by<=bx); the mirror
//      tile is written via an LDS transpose staging tile (PADW=130 keeps
//      both transpose-write banks and mirror-read banks conflict-free-ish,
//      and all global stores coalesced). q0 = min(floor(d*qscale),65535),
//      qscale 1024 (x) / 2048 (z). Global off-diag min/max of q reduced
//      block-wise into qstats (2 atomics per block).
//   3. rank kernel: 1024 blocks x 256 thr, 4 rows per block, register
//      prefetch of next row's data across the current row's barrier
//      phases. Global-normalized 11-bit bins (validated r7, absmax 0.0);
//      one ds_add_rtn pass counts AND yields intra-bin offsets; dual
//      scan; plain ds_read final pass; |rx-rz| inline.
//   4. finalize: 3 scalars.

#define N 4096
#define DX 512
#define DZ 64
#define NBIN 2048
#define NWRD (NBIN / 2)
#define RPB 4

typedef __attribute__((ext_vector_type(8))) short short8;
typedef __attribute__((ext_vector_type(4))) float float4v;

// stats word layout (u32 index into qstats base):
//   [0..1] rank_acc (u64)  [2..3] pd_acc (double)
//   [4] maxx [5] maxz      [6] minx [7] minz
#define ST_MAX 4
#define ST_MIN 6

// ---------------- async 16B global -> LDS ----------------
__device__ __forceinline__ void async16(const void* g, void* l) {
  __builtin_amdgcn_global_load_lds(
      (const __attribute__((address_space(1))) unsigned int*)(g),
      (__attribute__((address_space(3))) unsigned int*)(l), 16, 0, 0);
}

// ---------------- prep: norms + bf16 casts ----------------
__global__ __launch_bounds__(256) void prep_kernel(
    const float* __restrict__ x, const float* __restrict__ z,
    __hip_bfloat16* __restrict__ xb, __hip_bfloat16* __restrict__ zb,
    float* __restrict__ nx, float* __restrict__ nz) {
  int row = blockIdx.x;
  int tid = threadIdx.x;
  __shared__ float red[256];

  float sx = 0.f;
  for (int c = tid; c < DX; c += 256) {
    float v = x[(size_t)row * DX + c];
    xb[(size_t)row * DX + c] = __float2bfloat16(v);
    sx += v * v;
  }
  red[tid] = sx;
  __syncthreads();
  for (int s = 128; s > 0; s >>= 1) {
    if (tid < s) red[tid] += red[tid + s];
    __syncthreads();
  }
  if (tid == 0) nx[row] = red[0];
  __syncthreads();

  float sz = 0.f;
  if (tid < DZ) {
    float v = z[(size_t)row * DZ + tid];
    zb[(size_t)row * DZ + tid] = __float2bfloat16(v);
    sz = v * v;
  }
  red[tid] = sz;
  __syncthreads();
  for (int s = 128; s > 0; s >>= 1) {
    if (tid < s) red[tid] += red[tid + s];
    __syncthreads();
  }
  if (tid == 0) nz[row] = red[0];
}

// ------- bf16 MFMA Gram, symmetric tiles + quantized-distance epilogue ---
#define TILE 128
#define BK 32
#define PADW 130  // ctile row stride in u16 (65 u32 words: 65 % 32 == 1)

__global__ __launch_bounds__(256) void gram_dist_kernel(
    const __hip_bfloat16* __restrict__ Abf, const float* __restrict__ norms,
    unsigned short* __restrict__ distq, int K, float qscale,
    unsigned* __restrict__ qstats, int slot) {
  __shared__ short As[TILE * BK];                 // 8 KB
  __shared__ short Bs[TILE * BK];                 // 8 KB
  __shared__ unsigned short ctile[TILE * PADW];   // 32.5 KB transpose stage
  __shared__ unsigned mmx[8];

  int by = blockIdx.y, bx = blockIdx.x;
  if (by > bx) return;  // symmetric: upper-triangular tiles only

  int tid = threadIdx.x;
  int wave = tid >> 6, lane = tid & 63;
  int wr = wave >> 1, wc = wave & 1;
  int quad = lane >> 4, l15 = lane & 15;

  int rowBase = by * TILE;
  int colBase = bx * TILE;

  float4v acc[4][4];
#pragma unroll
  for (int mi = 0; mi < 4; ++mi)
#pragma unroll
    for (int ni = 0; ni < 4; ++ni) {
      float4v zv = {0.f, 0.f, 0.f, 0.f};
      acc[mi][ni] = zv;
    }

  const char* Ab = (const char*)Abf;
  const size_t rb = (size_t)K * 2;  // row bytes
  int chunk0 = wave * 2, chunk1 = wave * 2 + 1;
  int rl = lane >> 2;        // row within a 16-row chunk (4 lanes/row)
  int cl = (lane & 3) * 16;  // byte col within 64B row

  for (int kc = 0; kc < K; kc += BK) {
    const char* base = Ab + (size_t)kc * 2 + cl;
    async16(base + (size_t)(rowBase + chunk0 * 16 + rl) * rb,
            &As[chunk0 * 512]);
    async16(base + (size_t)(rowBase + chunk1 * 16 + rl) * rb,
            &As[chunk1 * 512]);
    async16(base + (size_t)(colBase + chunk0 * 16 + rl) * rb,
            &Bs[chunk0 * 512]);
    async16(base + (size_t)(colBase + chunk1 * 16 + rl) * rb,
            &Bs[chunk1 * 512]);
    __syncthreads();

    short8 a[4], b[4];
#pragma unroll
    for (int mi = 0; mi < 4; ++mi)
      a[mi] = *(const short8*)(&As[(wr * 64 + mi * 16 + l15) * BK + quad * 8]);
#pragma unroll
    for (int ni = 0; ni < 4; ++ni)
      b[ni] = *(const short8*)(&Bs[(wc * 64 + ni * 16 + l15) * BK + quad * 8]);
#pragma unroll
    for (int mi = 0; mi < 4; ++mi)
#pragma unroll
      for (int ni = 0; ni < 4; ++ni)
        acc[mi][ni] = __builtin_amdgcn_mfma_f32_16x16x32_bf16(
            a[mi], b[ni], acc[mi][ni], 0, 0, 0);
    __syncthreads();
  }

  // epilogue: quantize, direct-write upper tile, stage transpose in LDS
  unsigned mn = 0xFFFFu, mx = 0u;
#pragma unroll
  for (int mi = 0; mi < 4; ++mi) {
#pragma unroll
    for (int ni = 0; ni < 4; ++ni) {
      int colL = wc * 64 + ni * 16 + l15;
      int col = colBase + colL;
      float ncol = norms[col];
#pragma unroll
      for (int r = 0; r < 4; ++r) {
        int rowL = wr * 64 + mi * 16 + quad * 4 + r;
        int row = rowBase + rowL;
        float sq = norms[row] + ncol - 2.0f * acc[mi][ni][r];
        float d = sq > 0.f ? sqrtf(sq) : 0.f;
        if (row == col) d = 0.f;
        unsigned q = (unsigned)(d * qscale);
        q = q > 65535u ? 65535u : q;
        distq[(size_t)row * N + col] = (unsigned short)q;
        if (by != bx) ctile[colL * PADW + rowL] = (unsigned short)q;
        mx = max(mx, q);
        mn = min(mn, (row == col) ? 0xFFFFu : q);
      }
    }
  }
  __syncthreads();

  // mirror write (lower tile), coalesced rows read from transposed ctile
  if (by != bx) {
    const unsigned* cw = (const unsigned*)ctile;  // row stride 65 words
#pragma unroll
    for (int s = 0; s < 8; ++s) {
      int j = s * 16 + (tid >> 4);   // mirror row = col_local
      int k4 = (tid & 15) * 4;       // u32 chunk (8 u16 elements)
      uint4 v;
      v.x = cw[j * 65 + k4 + 0];
      v.y = cw[j * 65 + k4 + 1];
      v.z = cw[j * 65 + k4 + 2];
      v.w = cw[j * 65 + k4 + 3];
      *(uint4*)(distq + (size_t)(colBase + j) * N + rowBase + k4 * 2) = v;
    }
  }

  // block-level min/max reduce -> 2 device atomics per block
#pragma unroll
  for (int d = 32; d; d >>= 1) {
    mn = min(mn, (unsigned)__shfl_xor((int)mn, d, 64));
    mx = max(mx, (unsigned)__shfl_xor((int)mx, d, 64));
  }
  if (lane == 0) {
    mmx[wave] = mn;
    mmx[4 + wave] = mx;
  }
  __syncthreads();
  if (tid == 0) {
    unsigned bmn = min(min(mmx[0], mmx[1]), min(mmx[2], mmx[3]));
    unsigned bmx = max(max(mmx[4], mmx[5]), max(mmx[6], mmx[7]));
    atomicMin(&qstats[ST_MIN + slot], bmn);
    atomicMax(&qstats[ST_MAX + slot], bmx);
  }
}

// ---------------- counting-based per-row ranks (4 rows / block) ----------
__device__ __forceinline__ int hsw(int w) { return w ^ ((w >> 5) & 31); }

__global__ __launch_bounds__(256) void rank_kernel(
    const unsigned short* __restrict__ qx,
    const unsigned short* __restrict__ qz,
    const unsigned* __restrict__ qstats,
    unsigned long long* __restrict__ rank_acc, double* __restrict__ pd_acc) {
  __shared__ unsigned histX[NWRD];  // 4 KB
  __shared__ unsigned histZ[NWRD];  // 4 KB
  __shared__ unsigned xch[32];

  int t = threadIdx.x, lane = t & 63, wv = t >> 6;
  int row0 = (int)blockIdx.x * RPB;

  float lox = (float)(int)qstats[ST_MIN + 0];
  float scx = (float)(NBIN - 1) /
              (float)(int)max(1u, qstats[ST_MAX + 0] - qstats[ST_MIN + 0]);
  float loz = (float)(int)qstats[ST_MIN + 1];
  float scz = (float)(NBIN - 1) /
              (float)(int)max(1u, qstats[ST_MAX + 1] - qstats[ST_MIN + 1]);

  const uint4* px = (const uint4*)(qx + (size_t)row0 * N);
  const uint4* pz = (const uint4*)(qz + (size_t)row0 * N);

  // preload row 0 of this block
  uint4 cxa = px[t * 2], cxb = px[t * 2 + 1];
  uint4 cza = pz[t * 2], czb = pz[t * 2 + 1];

  float pd = 0.f;
  int rsum = 0;

#pragma unroll 1
  for (int r = 0; r < RPB; ++r) {
    // zero hists
#pragma unroll
    for (int i = 0; i < 4; ++i) {
      histX[t + 256 * i] = 0u;
      histZ[t + 256 * i] = 0u;
    }
    // prefetch next row while this row's LDS phases run
    uint4 nxa = cxa, nxb = cxb, nza = cza, nzb = czb;
    if (r + 1 < RPB) {
      const uint4* npx = px + (size_t)(r + 1) * (N / 8);
      const uint4* npz = pz + (size_t)(r + 1) * (N / 8);
      nxa = npx[t * 2];
      nxb = npx[t * 2 + 1];
      nza = npz[t * 2];
      nzb = npz[t * 2 + 1];
    }

    unsigned xw[8] = {cxa.x, cxa.y, cxa.z, cxa.w, cxb.x, cxb.y, cxb.z, cxb.w};
    unsigned zw[8] = {cza.x, cza.y, cza.z, cza.w, czb.x, czb.y, czb.z, czb.w};

    // pairdist partial
#pragma unroll
    for (int c = 0; c < 16; ++c) {
      unsigned qxv = (xw[c >> 1] >> ((c & 1) * 16)) & 0xFFFFu;
      unsigned qzv = (zw[c >> 1] >> ((c & 1) * 16)) & 0xFFFFu;
      // dz-dx = ((qz+.5)/2048 - (qx+.5)/1024) = (qz - 2*qx - 0.5)/2048
      float tv = (float)(int)qzv - 2.0f * (float)(int)qxv - 0.5f;
      pd += tv * tv;
    }
    __syncthreads();  // hist zeroing complete

    // single atomic pass: count AND capture intra-bin offset
    unsigned oxp[8], ozp[8];
#pragma unroll
    for (int c = 0; c < 16; ++c) {
      unsigned qxv = (xw[c >> 1] >> ((c & 1) * 16)) & 0xFFFFu;
      unsigned qzv = (zw[c >> 1] >> ((c & 1) * 16)) & 0xFFFFu;
      unsigned bx = (unsigned)(int)fminf(
          fmaxf(((float)(int)qxv - lox) * scx, 0.0f), (float)(NBIN - 1));
      unsigned bz = (unsigned)(int)fminf(
          fmaxf(((float)(int)qzv - loz) * scz, 0.0f), (float)(NBIN - 1));
      unsigned shx = (bx & 1) * 16, shz = (bz & 1) * 16;
      unsigned ox =
          (atomicAdd(&histX[hsw((int)(bx >> 1))], 1u << shx) >> shx) & 0xFFFFu;
      unsigned oz =
          (atomicAdd(&histZ[hsw((int)(bz >> 1))], 1u << shz) >> shz) & 0xFFFFu;
      if (c & 1) {
        oxp[c >> 1] |= ox << 16;
        ozp[c >> 1] |= oz << 16;
      } else {
        oxp[c >> 1] = ox;
        ozp[c >> 1] = oz;
      }
    }
    __syncthreads();

    // dual exclusive scan: waves 0-1 -> histX, waves 2-3 -> histZ
    {
      unsigned* h = (wv < 2) ? histX : histZ;
      int t2 = t & 127;
      int wb = t2 * 8;
      unsigned run = 0;
#pragma unroll
      for (int c = 0; c < 8; ++c) {
        int w = hsw(wb + c);
        unsigned v = h[w];
        unsigned lo = v & 0xFFFFu;
        h[w] = run | ((run + lo) << 16);
        run += lo + (v >> 16);
      }
      unsigned incl = run;
#pragma unroll
      for (int d = 1; d < 64; d <<= 1) {
        unsigned o = (unsigned)__shfl_up((int)incl, d, 64);
        if (lane >= d) incl += o;
      }
      if (lane == 63) xch[16 + wv] = incl;
      __syncthreads();
      unsigned base = incl - run;              // exclusive within my wave
      if (wv & 1) base += xch[16 + (wv - 1)];  // add lower wave of my hist
      unsigned add = base * 0x10001u;
#pragma unroll
      for (int c = 0; c < 8; ++c) h[hsw(wb + c)] += add;
    }
    __syncthreads();

    // final pass: plain ds_read of scanned bases; |rx-rz| inline
#pragma unroll
    for (int c = 0; c < 16; ++c) {
      unsigned qxv = (xw[c >> 1] >> ((c & 1) * 16)) & 0xFFFFu;
      unsigned qzv = (zw[c >> 1] >> ((c & 1) * 16)) & 0xFFFFu;
      unsigned bx = (unsigned)(int)fminf(
          fmaxf(((float)(int)qxv - lox) * scx, 0.0f), (float)(NBIN - 1));
      unsigned bz = (unsigned)(int)fminf(
          fmaxf(((float)(int)qzv - loz) * scz, 0.0f), (float)(NBIN - 1));
      unsigned shx = (bx & 1) * 16, shz = (bz & 1) * 16;
      unsigned basex = (histX[hsw((int)(bx >> 1))] >> shx) & 0xFFFFu;
      unsigned basez = (histZ[hsw((int)(bz >> 1))] >> shz) & 0xFFFFu;
      int rx = (int)(basex + ((oxp[c >> 1] >> ((c & 1) * 16)) & 0xFFFFu));
      int rz = (int)(basez + ((ozp[c >> 1] >> ((c & 1) * 16)) & 0xFFFFu));
      int d = rx - rz;
      rsum += d < 0 ? -d : d;
    }
    __syncthreads();  // protect hist re-zero next iteration

    cxa = nxa;
    cxb = nxb;
    cza = nza;
    czb = nzb;
  }

  // block reduce + global atomics
#pragma unroll
  for (int d = 32; d; d >>= 1) {
    rsum += __shfl_xor(rsum, d, 64);
    pd += __shfl_xor(pd, d, 64);
  }
  if (lane == 0) {
    xch[wv] = (unsigned)rsum;
    ((float*)xch)[8 + wv] = pd;
  }
  __syncthreads();
  if (t == 0) {
    unsigned long long rtot =
        (unsigned long long)xch[0] + xch[1] + xch[2] + xch[3];
    float ptot = ((float*)xch)[8] + ((float*)xch)[9] + ((float*)xch)[10] +
                 ((float*)xch)[11];
    atomicAdd(rank_acc, rtot);
    atomicAdd(pd_acc, (double)ptot);
  }
}

// ---------------- finalize ----------------
__global__ void finalize_kernel(const unsigned long long* __restrict__ racc,
                                const double* __restrict__ pacc,
                                float* __restrict__ out) {
  double inv = 1.0 / ((double)N * (double)N);
  double rank_loss = (double)(*racc) * inv / 32.0;  // K = 32
  double pd = (*pacc) * inv / (2048.0 * 2048.0);    // undo q scaling
  out[0] = (float)(rank_loss + 0.5 * pd);
  out[1] = (float)rank_loss;
  out[2] = (float)pd;
}

// ---------------- launch ----------------
extern "C" void kernel_launch(void* const* d_in, const int* in_sizes, int n_in,
                              void* d_out, int out_size, void* d_ws,
                              size_t ws_size, hipStream_t stream) {
  (void)in_sizes; (void)n_in; (void)out_size; (void)ws_size;
  const float* x = (const float*)d_in[0];
  const float* z = (const float*)d_in[1];
  float* out = (float*)d_out;

  char* w = (char*)d_ws;
  unsigned short* qx16 = (unsigned short*)(w);             // 32 MB
  unsigned short* qz16 = (unsigned short*)(w + 33554432);  // 32 MB
  __hip_bfloat16* xb = (__hip_bfloat16*)(w + 67108864);    // 4 MB
  __hip_bfloat16* zb = (__hip_bfloat16*)(w + 71303168);    // 0.5 MB
  float* nx = (float*)(w + 71827456);
  float* nz = (float*)(w + 71843840);
  unsigned* qstats = (unsigned*)(w + 71860224);
  unsigned long long* rank_acc = (unsigned long long*)(w + 71860224);
  double* pd_acc = (double*)(w + 71860224 + 8);

  // [0..23] rank_acc, pd_acc, maxx, maxz -> 0 ; [24..31] minx, minz -> ~0
  hipMemsetAsync(w + 71860224, 0, 24, stream);
  hipMemsetAsync(w + 71860224 + 24, 0xFF, 8, stream);

  prep_kernel<<<N, 256, 0, stream>>>(x, z, xb, zb, nx, nz);

  dim3 ggrid(N / TILE, N / TILE);
  gram_dist_kernel<<<ggrid, 256, 0, stream>>>(xb, nx, qx16, DX, 1024.0f,
                                              qstats, 0);
  gram_dist_kernel<<<ggrid, 256, 0, stream>>>(zb, nz, qz16, DZ, 2048.0f,
                                              qstats, 1);

  rank_kernel<<<N / RPB, 256, 0, stream>>>(qx16, qz16, qstats, rank_acc,
                                           pd_acc);

  finalize_kernel<<<1, 1, 0, stream>>>(rank_acc, pd_acc, out);
}

// Round 9
// 186.368 us; speedup vs baseline: 1.8099x; 1.0589x over previous
//
#include <hip/hip_runtime.h>
#include <hip/hip_bf16.h>

// Problem: N=4096, Dx=512, Dz=64.
// out[0]=total, out[1]=rank_loss, out[2]=pairdist_loss (f32).
//
// Pipeline:
//   1. prep: nx[i]=sum x[i]^2 (f32), nz likewise; cast x,z to bf16.
//   2. gram_dist x2 (bf16 MFMA, global_load_lds staging, SYMMETRIC upper
//      tiles only). Epilogue stages the quantized tile in LDS so ALL
//      global dist writes are coalesced uint4 (r8 bottleneck: 64 scalar
//      2B stores/thread = 8.6M store instrs ~= the whole 55 us dispatch).
//      q0 = min(floor(d*qscale),65535), qscale 1024 (x) / 2048 (z).
//      Global off-diag min/max reduced block-wise (2 atomics/block).
//   3. rank kernel: 1024 blocks x 256 thr, 4 rows/block, register
//      prefetch; global-normalized 11-bit bins; ds_add_rtn count+offset
//      pass; dual scan; plain ds_read final pass; |rx-rz| inline.
//   4. finalize: 3 scalars.

#define N 4096
#define DX 512
#define DZ 64
#define NBIN 2048
#define NWRD (NBIN / 2)
#define RPB 4

typedef __attribute__((ext_vector_type(8))) short short8;
typedef __attribute__((ext_vector_type(4))) float float4v;

// stats word layout (u32 index into qstats base):
//   [0..1] rank_acc (u64)  [2..3] pd_acc (double)
//   [4] maxx [5] maxz      [6] minx [7] minz
#define ST_MAX 4
#define ST_MIN 6

// ---------------- async 16B global -> LDS ----------------
__device__ __forceinline__ void async16(const void* g, void* l) {
  __builtin_amdgcn_global_load_lds(
      (const __attribute__((address_space(1))) unsigned int*)(g),
      (__attribute__((address_space(3))) unsigned int*)(l), 16, 0, 0);
}

// ---------------- prep: norms + bf16 casts ----------------
__global__ __launch_bounds__(256) void prep_kernel(
    const float* __restrict__ x, const float* __restrict__ z,
    __hip_bfloat16* __restrict__ xb, __hip_bfloat16* __restrict__ zb,
    float* __restrict__ nx, float* __restrict__ nz) {
  int row = blockIdx.x;
  int tid = threadIdx.x;
  __shared__ float red[256];

  float sx = 0.f;
  for (int c = tid; c < DX; c += 256) {
    float v = x[(size_t)row * DX + c];
    xb[(size_t)row * DX + c] = __float2bfloat16(v);
    sx += v * v;
  }
  red[tid] = sx;
  __syncthreads();
  for (int s = 128; s > 0; s >>= 1) {
    if (tid < s) red[tid] += red[tid + s];
    __syncthreads();
  }
  if (tid == 0) nx[row] = red[0];
  __syncthreads();

  float sz = 0.f;
  if (tid < DZ) {
    float v = z[(size_t)row * DZ + tid];
    zb[(size_t)row * DZ + tid] = __float2bfloat16(v);
    sz = v * v;
  }
  red[tid] = sz;
  __syncthreads();
  for (int s = 128; s > 0; s >>= 1) {
    if (tid < s) red[tid] += red[tid + s];
    __syncthreads();
  }
  if (tid == 0) nz[row] = red[0];
}

// ------- bf16 MFMA Gram, symmetric tiles + staged coalesced epilogue -----
#define TILE 128
#define BK 32
#define PADW 132  // ctile row stride in u16; 66 words (even -> 8B-aligned b64)

__global__ __launch_bounds__(256) void gram_dist_kernel(
    const __hip_bfloat16* __restrict__ Abf, const float* __restrict__ norms,
    unsigned short* __restrict__ distq, int K, float qscale,
    unsigned* __restrict__ qstats, int slot) {
  __shared__ short As[TILE * BK];                // 8 KB
  __shared__ short Bs[TILE * BK];                // 8 KB
  __shared__ unsigned short ctile[TILE * PADW];  // 33 KB stage
  __shared__ unsigned mmx[8];

  int by = blockIdx.y, bx = blockIdx.x;
  if (by > bx) return;  // symmetric: upper-triangular tiles only

  int tid = threadIdx.x;
  int wave = tid >> 6, lane = tid & 63;
  int wr = wave >> 1, wc = wave & 1;
  int quad = lane >> 4, l15 = lane & 15;

  int rowBase = by * TILE;
  int colBase = bx * TILE;

  float4v acc[4][4];
#pragma unroll
  for (int mi = 0; mi < 4; ++mi)
#pragma unroll
    for (int ni = 0; ni < 4; ++ni) {
      float4v zv = {0.f, 0.f, 0.f, 0.f};
      acc[mi][ni] = zv;
    }

  const char* Ab = (const char*)Abf;
  const size_t rb = (size_t)K * 2;  // row bytes
  int chunk0 = wave * 2, chunk1 = wave * 2 + 1;
  int rl = lane >> 2;        // row within a 16-row chunk (4 lanes/row)
  int cl = (lane & 3) * 16;  // byte col within 64B row

  for (int kc = 0; kc < K; kc += BK) {
    const char* base = Ab + (size_t)kc * 2 + cl;
    async16(base + (size_t)(rowBase + chunk0 * 16 + rl) * rb,
            &As[chunk0 * 512]);
    async16(base + (size_t)(rowBase + chunk1 * 16 + rl) * rb,
            &As[chunk1 * 512]);
    async16(base + (size_t)(colBase + chunk0 * 16 + rl) * rb,
            &Bs[chunk0 * 512]);
    async16(base + (size_t)(colBase + chunk1 * 16 + rl) * rb,
            &Bs[chunk1 * 512]);
    __syncthreads();

    short8 a[4], b[4];
#pragma unroll
    for (int mi = 0; mi < 4; ++mi)
      a[mi] = *(const short8*)(&As[(wr * 64 + mi * 16 + l15) * BK + quad * 8]);
#pragma unroll
    for (int ni = 0; ni < 4; ++ni)
      b[ni] = *(const short8*)(&Bs[(wc * 64 + ni * 16 + l15) * BK + quad * 8]);
#pragma unroll
    for (int mi = 0; mi < 4; ++mi)
#pragma unroll
      for (int ni = 0; ni < 4; ++ni)
        acc[mi][ni] = __builtin_amdgcn_mfma_f32_16x16x32_bf16(
            a[mi], b[ni], acc[mi][ni], 0, 0, 0);
    __syncthreads();
  }

  // ---- quantize: stage [row][col] in LDS + keep packed u64 per column ----
  unsigned mn = 0xFFFFu, mx = 0u;
  unsigned long long qp[4][4];
#pragma unroll
  for (int mi = 0; mi < 4; ++mi) {
#pragma unroll
    for (int ni = 0; ni < 4; ++ni) {
      int colL = wc * 64 + ni * 16 + l15;
      float ncol = norms[colBase + colL];
      unsigned long long pk = 0ull;
#pragma unroll
      for (int r = 0; r < 4; ++r) {
        int rowL = wr * 64 + mi * 16 + quad * 4 + r;
        int row = rowBase + rowL;
        float sq = norms[row] + ncol - 2.0f * acc[mi][ni][r];
        float d = sq > 0.f ? sqrtf(sq) : 0.f;
        if (row == colBase + colL) d = 0.f;
        unsigned q = (unsigned)(d * qscale);
        q = q > 65535u ? 65535u : q;
        ctile[rowL * PADW + colL] = (unsigned short)q;
        pk |= (unsigned long long)q << (16 * r);
        mx = max(mx, q);
        mn = min(mn, (row == colBase + colL) ? 0xFFFFu : q);
      }
      qp[mi][ni] = pk;
    }
  }
  __syncthreads();

  // ---- pass A: upper tile, coalesced uint4 rows from ctile[row][col] ----
  {
    const unsigned* cw = (const unsigned*)ctile;  // word rows, stride 66
    int i0 = tid >> 4, k4 = (tid & 15) * 4;
#pragma unroll
    for (int s = 0; s < 8; ++s) {
      int i = s * 16 + i0;
      int wb = i * (PADW / 2) + k4;
      uint4 v;
      v.x = cw[wb + 0];
      v.y = cw[wb + 1];
      v.z = cw[wb + 2];
      v.w = cw[wb + 3];
      *(uint4*)(distq + (size_t)(rowBase + i) * N + colBase + (tid & 15) * 8) =
          v;
    }
  }

  // ---- pass B: mirror tile via transposed restage (off-diag only) ----
  if (by != bx) {
    __syncthreads();  // pass-A reads done before overwrite
#pragma unroll
    for (int mi = 0; mi < 4; ++mi)
#pragma unroll
      for (int ni = 0; ni < 4; ++ni) {
        int colL = wc * 64 + ni * 16 + l15;
        int rowL0 = wr * 64 + mi * 16 + quad * 4;
        *(unsigned long long*)&ctile[colL * PADW + rowL0] = qp[mi][ni];
      }
    __syncthreads();
    const unsigned* cw = (const unsigned*)ctile;
    int j0 = tid >> 4, k4 = (tid & 15) * 4;
#pragma unroll
    for (int s = 0; s < 8; ++s) {
      int j = s * 16 + j0;
      int wb = j * (PADW / 2) + k4;
      uint4 v;
      v.x = cw[wb + 0];
      v.y = cw[wb + 1];
      v.z = cw[wb + 2];
      v.w = cw[wb + 3];
      *(uint4*)(distq + (size_t)(colBase + j) * N + rowBase + (tid & 15) * 8) =
          v;
    }
  }

  // ---- block-level min/max reduce -> 2 device atomics per block ----
#pragma unroll
  for (int d = 32; d; d >>= 1) {
    mn = min(mn, (unsigned)__shfl_xor((int)mn, d, 64));
    mx = max(mx, (unsigned)__shfl_xor((int)mx, d, 64));
  }
  if (lane == 0) {
    mmx[wave] = mn;
    mmx[4 + wave] = mx;
  }
  __syncthreads();
  if (tid == 0) {
    unsigned bmn = min(min(mmx[0], mmx[1]), min(mmx[2], mmx[3]));
    unsigned bmx = max(max(mmx[4], mmx[5]), max(mmx[6], mmx[7]));
    atomicMin(&qstats[ST_MIN + slot], bmn);
    atomicMax(&qstats[ST_MAX + slot], bmx);
  }
}

// ---------------- counting-based per-row ranks (4 rows / block) ----------
__device__ __forceinline__ int hsw(int w) { return w ^ ((w >> 5) & 31); }

__global__ __launch_bounds__(256) void rank_kernel(
    const unsigned short* __restrict__ qx,
    const unsigned short* __restrict__ qz,
    const unsigned* __restrict__ qstats,
    unsigned long long* __restrict__ rank_acc, double* __restrict__ pd_acc) {
  __shared__ unsigned histX[NWRD];  // 4 KB
  __shared__ unsigned histZ[NWRD];  // 4 KB
  __shared__ unsigned xch[32];

  int t = threadIdx.x, lane = t & 63, wv = t >> 6;
  int row0 = (int)blockIdx.x * RPB;

  float lox = (float)(int)qstats[ST_MIN + 0];
  float scx = (float)(NBIN - 1) /
              (float)(int)max(1u, qstats[ST_MAX + 0] - qstats[ST_MIN + 0]);
  float loz = (float)(int)qstats[ST_MIN + 1];
  float scz = (float)(NBIN - 1) /
              (float)(int)max(1u, qstats[ST_MAX + 1] - qstats[ST_MIN + 1]);

  const uint4* px = (const uint4*)(qx + (size_t)row0 * N);
  const uint4* pz = (const uint4*)(qz + (size_t)row0 * N);

  // preload row 0 of this block
  uint4 cxa = px[t * 2], cxb = px[t * 2 + 1];
  uint4 cza = pz[t * 2], czb = pz[t * 2 + 1];

  float pd = 0.f;
  int rsum = 0;

#pragma unroll 1
  for (int r = 0; r < RPB; ++r) {
    // zero hists
#pragma unroll
    for (int i = 0; i < 4; ++i) {
      histX[t + 256 * i] = 0u;
      histZ[t + 256 * i] = 0u;
    }
    // prefetch next row while this row's LDS phases run
    uint4 nxa = cxa, nxb = cxb, nza = cza, nzb = czb;
    if (r + 1 < RPB) {
      const uint4* npx = px + (size_t)(r + 1) * (N / 8);
      const uint4* npz = pz + (size_t)(r + 1) * (N / 8);
      nxa = npx[t * 2];
      nxb = npx[t * 2 + 1];
      nza = npz[t * 2];
      nzb = npz[t * 2 + 1];
    }

    unsigned xw[8] = {cxa.x, cxa.y, cxa.z, cxa.w, cxb.x, cxb.y, cxb.z, cxb.w};
    unsigned zw[8] = {cza.x, cza.y, cza.z, cza.w, czb.x, czb.y, czb.z, czb.w};

    // pairdist partial
#pragma unroll
    for (int c = 0; c < 16; ++c) {
      unsigned qxv = (xw[c >> 1] >> ((c & 1) * 16)) & 0xFFFFu;
      unsigned qzv = (zw[c >> 1] >> ((c & 1) * 16)) & 0xFFFFu;
      // dz-dx = ((qz+.5)/2048 - (qx+.5)/1024) = (qz - 2*qx - 0.5)/2048
      float tv = (float)(int)qzv - 2.0f * (float)(int)qxv - 0.5f;
      pd += tv * tv;
    }
    __syncthreads();  // hist zeroing complete

    // single atomic pass: count AND capture intra-bin offset
    unsigned oxp[8], ozp[8];
#pragma unroll
    for (int c = 0; c < 16; ++c) {
      unsigned qxv = (xw[c >> 1] >> ((c & 1) * 16)) & 0xFFFFu;
      unsigned qzv = (zw[c >> 1] >> ((c & 1) * 16)) & 0xFFFFu;
      unsigned bx = (unsigned)(int)fminf(
          fmaxf(((float)(int)qxv - lox) * scx, 0.0f), (float)(NBIN - 1));
      unsigned bz = (unsigned)(int)fminf(
          fmaxf(((float)(int)qzv - loz) * scz, 0.0f), (float)(NBIN - 1));
      unsigned shx = (bx & 1) * 16, shz = (bz & 1) * 16;
      unsigned ox =
          (atomicAdd(&histX[hsw((int)(bx >> 1))], 1u << shx) >> shx) & 0xFFFFu;
      unsigned oz =
          (atomicAdd(&histZ[hsw((int)(bz >> 1))], 1u << shz) >> shz) & 0xFFFFu;
      if (c & 1) {
        oxp[c >> 1] |= ox << 16;
        ozp[c >> 1] |= oz << 16;
      } else {
        oxp[c >> 1] = ox;
        ozp[c >> 1] = oz;
      }
    }
    __syncthreads();

    // dual exclusive scan: waves 0-1 -> histX, waves 2-3 -> histZ
    {
      unsigned* h = (wv < 2) ? histX : histZ;
      int t2 = t & 127;
      int wb = t2 * 8;
      unsigned run = 0;
#pragma unroll
      for (int c = 0; c < 8; ++c) {
        int w = hsw(wb + c);
        unsigned v = h[w];
        unsigned lo = v & 0xFFFFu;
        h[w] = run | ((run + lo) << 16);
        run += lo + (v >> 16);
      }
      unsigned incl = run;
#pragma unroll
      for (int d = 1; d < 64; d <<= 1) {
        unsigned o = (unsigned)__shfl_up((int)incl, d, 64);
        if (lane >= d) incl += o;
      }
      if (lane == 63) xch[16 + wv] = incl;
      __syncthreads();
      unsigned base = incl - run;              // exclusive within my wave
      if (wv & 1) base += xch[16 + (wv - 1)];  // add lower wave of my hist
      unsigned add = base * 0x10001u;
#pragma unroll
      for (int c = 0; c < 8; ++c) h[hsw(wb + c)] += add;
    }
    __syncthreads();

    // final pass: plain ds_read of scanned bases; |rx-rz| inline
#pragma unroll
    for (int c = 0; c < 16; ++c) {
      unsigned qxv = (xw[c >> 1] >> ((c & 1) * 16)) & 0xFFFFu;
      unsigned qzv = (zw[c >> 1] >> ((c & 1) * 16)) & 0xFFFFu;
      unsigned bx = (unsigned)(int)fminf(
          fmaxf(((float)(int)qxv - lox) * scx, 0.0f), (float)(NBIN - 1));
      unsigned bz = (unsigned)(int)fminf(
          fmaxf(((float)(int)qzv - loz) * scz, 0.0f), (float)(NBIN - 1));
      unsigned shx = (bx & 1) * 16, shz = (bz & 1) * 16;
      unsigned basex = (histX[hsw((int)(bx >> 1))] >> shx) & 0xFFFFu;
      unsigned basez = (histZ[hsw((int)(bz >> 1))] >> shz) & 0xFFFFu;
      int rx = (int)(basex + ((oxp[c >> 1] >> ((c & 1) * 16)) & 0xFFFFu));
      int rz = (int)(basez + ((ozp[c >> 1] >> ((c & 1) * 16)) & 0xFFFFu));
      int d = rx - rz;
      rsum += d < 0 ? -d : d;
    }
    __syncthreads();  // protect hist re-zero next iteration

    cxa = nxa;
    cxb = nxb;
    cza = nza;
    czb = nzb;
  }

  // block reduce + global atomics
#pragma unroll
  for (int d = 32; d; d >>= 1) {
    rsum += __shfl_xor(rsum, d, 64);
    pd += __shfl_xor(pd, d, 64);
  }
  if (lane == 0) {
    xch[wv] = (unsigned)rsum;
    ((float*)xch)[8 + wv] = pd;
  }
  __syncthreads();
  if (t == 0) {
    unsigned long long rtot =
        (unsigned long long)xch[0] + xch[1] + xch[2] + xch[3];
    float ptot = ((float*)xch)[8] + ((float*)xch)[9] + ((float*)xch)[10] +
                 ((float*)xch)[11];
    atomicAdd(rank_acc, rtot);
    atomicAdd(pd_acc, (double)ptot);
  }
}

// ---------------- finalize ----------------
__global__ void finalize_kernel(const unsigned long long* __restrict__ racc,
                                const double* __restrict__ pacc,
                                float* __restrict__ out) {
  double inv = 1.0 / ((double)N * (double)N);
  double rank_loss = (double)(*racc) * inv / 32.0;  // K = 32
  double pd = (*pacc) * inv / (2048.0 * 2048.0);    // undo q scaling
  out[0] = (float)(rank_loss + 0.5 * pd);
  out[1] = (float)rank_loss;
  out[2] = (float)pd;
}

// ---------------- launch ----------------
extern "C" void kernel_launch(void* const* d_in, const int* in_sizes, int n_in,
                              void* d_out, int out_size, void* d_ws,
                              size_t ws_size, hipStream_t stream) {
  (void)in_sizes; (void)n_in; (void)out_size; (void)ws_size;
  const float* x = (const float*)d_in[0];
  const float* z = (const float*)d_in[1];
  float* out = (float*)d_out;

  char* w = (char*)d_ws;
  unsigned short* qx16 = (unsigned short*)(w);             // 32 MB
  unsigned short* qz16 = (unsigned short*)(w + 33554432);  // 32 MB
  __hip_bfloat16* xb = (__hip_bfloat16*)(w + 67108864);    // 4 MB
  __hip_bfloat16* zb = (__hip_bfloat16*)(w + 71303168);    // 0.5 MB
  float* nx = (float*)(w + 71827456);
  float* nz = (float*)(w + 71843840);
  unsigned* qstats = (unsigned*)(w + 71860224);
  unsigned long long* rank_acc = (unsigned long long*)(w + 71860224);
  double* pd_acc = (double*)(w + 71860224 + 8);

  // [0..23] rank_acc, pd_acc, maxx, maxz -> 0 ; [24..31] minx, minz -> ~0
  hipMemsetAsync(w + 71860224, 0, 24, stream);
  hipMemsetAsync(w + 71860224 + 24, 0xFF, 8, stream);

  prep_kernel<<<N, 256, 0, stream>>>(x, z, xb, zb, nx, nz);

  dim3 ggrid(N / TILE, N / TILE);
  gram_dist_kernel<<<ggrid, 256, 0, stream>>>(xb, nx, qx16, DX, 1024.0f,
                                              qstats, 0);
  gram_dist_kernel<<<ggrid, 256, 0, stream>>>(zb, nz, qz16, DZ, 2048.0f,
                                              qstats, 1);

  rank_kernel<<<N / RPB, 256, 0, stream>>>(qx16, qz16, qstats, rank_acc,
                                           pd_acc);

  finalize_kernel<<<1, 1, 0, stream>>>(rank_acc, pd_acc, out);
}

// Round 11
// 185.765 us; speedup vs baseline: 1.8158x; 1.0032x over previous
//
#include <hip/hip_runtime.h>
#include <hip/hip_bf16.h>

// Problem: N=4096, Dx=512, Dz=64.
// out[0]=total, out[1]=rank_loss, out[2]=pairdist_loss (f32).
//
// Pipeline:
//   1. prep: nx[i]=sum x[i]^2 (f32), nz likewise; cast x,z to bf16.
//   2. gram_dist x2 (bf16 MFMA, SYMMETRIC): compact 528-block triangular
//      grid (no dead blocks); double-buffered global_load_lds staging with
//      prefetch issued during compute; epilogue stages quantized tile in
//      LDS (aliased over staging buffers -> 34 KB block LDS, 4 blocks/CU)
//      so all dist writes are coalesced uint4. q0=min(floor(d*qscale),
//      65535), qscale 1024 (x) / 2048 (z). min/max: 2 atomics/block.
//      NOTE: LDS buffer pointers derived via byte offsets each use — an
//      array of LDS pointers fails to compile on gfx950 (addrspacecast
//      static initializer, round-10 failure).
//   3. rank kernel: 1024 blocks x 256 thr, 4 rows/block, register
//      prefetch; global-normalized 11-bit bins; ds_add_rtn count+offset
//      pass; dual scan; plain ds_read final pass; |rx-rz| inline.
//   4. finalize: 3 scalars.

#define N 4096
#define DX 512
#define DZ 64
#define NBIN 2048
#define NWRD (NBIN / 2)
#define RPB 4

typedef __attribute__((ext_vector_type(8))) short short8;
typedef __attribute__((ext_vector_type(4))) float float4v;

// stats word layout (u32 index into qstats base):
//   [0..1] rank_acc (u64)  [2..3] pd_acc (double)
//   [4] maxx [5] maxz      [6] minx [7] minz
#define ST_MAX 4
#define ST_MIN 6

// ---------------- async 16B global -> LDS ----------------
__device__ __forceinline__ void async16(const void* g, void* l) {
  __builtin_amdgcn_global_load_lds(
      (const __attribute__((address_space(1))) unsigned int*)(g),
      (__attribute__((address_space(3))) unsigned int*)(l), 16, 0, 0);
}

// ---------------- prep: norms + bf16 casts ----------------
__global__ __launch_bounds__(256) void prep_kernel(
    const float* __restrict__ x, const float* __restrict__ z,
    __hip_bfloat16* __restrict__ xb, __hip_bfloat16* __restrict__ zb,
    float* __restrict__ nx, float* __restrict__ nz) {
  int row = blockIdx.x;
  int tid = threadIdx.x;
  __shared__ float red[256];

  float sx = 0.f;
  for (int c = tid; c < DX; c += 256) {
    float v = x[(size_t)row * DX + c];
    xb[(size_t)row * DX + c] = __float2bfloat16(v);
    sx += v * v;
  }
  red[tid] = sx;
  __syncthreads();
  for (int s = 128; s > 0; s >>= 1) {
    if (tid < s) red[tid] += red[tid + s];
    __syncthreads();
  }
  if (tid == 0) nx[row] = red[0];
  __syncthreads();

  float sz = 0.f;
  if (tid < DZ) {
    float v = z[(size_t)row * DZ + tid];
    zb[(size_t)row * DZ + tid] = __float2bfloat16(v);
    sz = v * v;
  }
  red[tid] = sz;
  __syncthreads();
  for (int s = 128; s > 0; s >>= 1) {
    if (tid < s) red[tid] += red[tid + s];
    __syncthreads();
  }
  if (tid == 0) nz[row] = red[0];
}

// ------- bf16 MFMA Gram, symmetric compact grid, dbuf staging ------------
#define TILE 128
#define BK 32
#define PADW 132  // ctile row stride in u16; 66 words (even -> 8B-aligned b64)
#define NT 32     // tiles per dimension
#define NTRI 528  // NT*(NT+1)/2

__global__ __launch_bounds__(256) void gram_dist_kernel(
    const __hip_bfloat16* __restrict__ Abf, const float* __restrict__ norms,
    unsigned short* __restrict__ distq, int K, float qscale,
    unsigned* __restrict__ qstats, int slot) {
  // staging dbuf (2x16 KB) aliased with ctile (33 KB): 33792 B total
  __shared__ alignas(16) char smem[TILE * PADW * 2];
  __shared__ unsigned mmx[8];

  unsigned short* ctile = (unsigned short*)smem;

  // compact upper-triangular decode: row-major rows by=0..31, len 32-by
  int idx = (int)blockIdx.x;
  int by = (int)((65.0f - sqrtf(4225.0f - 8.0f * (float)idx)) * 0.5f);
  while (((by + 1) * (65 - (by + 1))) / 2 <= idx) ++by;
  while ((by * (65 - by)) / 2 > idx) --by;
  int bx = by + (idx - (by * (65 - by)) / 2);

  int tid = threadIdx.x;
  int wave = tid >> 6, lane = tid & 63;
  int wr = wave >> 1, wc = wave & 1;
  int quad = lane >> 4, l15 = lane & 15;

  int rowBase = by * TILE;
  int colBase = bx * TILE;

  float4v acc[4][4];
#pragma unroll
  for (int mi = 0; mi < 4; ++mi)
#pragma unroll
    for (int ni = 0; ni < 4; ++ni) {
      float4v zv = {0.f, 0.f, 0.f, 0.f};
      acc[mi][ni] = zv;
    }

  const char* Ab = (const char*)Abf;
  const size_t rb = (size_t)K * 2;  // row bytes
  int chunk0 = wave * 2, chunk1 = wave * 2 + 1;
  int rl = lane >> 2;        // row within a 16-row chunk (4 lanes/row)
  int cl = (lane & 3) * 16;  // byte col within 64B row

  // stage K-chunk kc into buffer b (byte-offset derived LDS pointers)
  auto stage = [&](int kc, int b) {
    const char* base = Ab + (size_t)kc * 2 + cl;
    short* sA = (short*)(smem + b * 16384);
    short* sB = (short*)(smem + b * 16384 + 8192);
    async16(base + (size_t)(rowBase + chunk0 * 16 + rl) * rb,
            &sA[chunk0 * 512]);
    async16(base + (size_t)(rowBase + chunk1 * 16 + rl) * rb,
            &sA[chunk1 * 512]);
    async16(base + (size_t)(colBase + chunk0 * 16 + rl) * rb,
            &sB[chunk0 * 512]);
    async16(base + (size_t)(colBase + chunk1 * 16 + rl) * rb,
            &sB[chunk1 * 512]);
  };

  stage(0, 0);  // preload first chunk
  int ib = 0;
  for (int kc = 0; kc < K; kc += BK, ib ^= 1) {
    __syncthreads();  // drains current buf's staging; prev readers done
    if (kc + BK < K) stage(kc + BK, ib ^ 1);  // in flight during MFMA

    const short* As = (const short*)(smem + ib * 16384);
    const short* Bs = (const short*)(smem + ib * 16384 + 8192);
    short8 a[4], b[4];
#pragma unroll
    for (int mi = 0; mi < 4; ++mi)
      a[mi] = *(const short8*)(&As[(wr * 64 + mi * 16 + l15) * BK + quad * 8]);
#pragma unroll
    for (int ni = 0; ni < 4; ++ni)
      b[ni] = *(const short8*)(&Bs[(wc * 64 + ni * 16 + l15) * BK + quad * 8]);
#pragma unroll
    for (int mi = 0; mi < 4; ++mi)
#pragma unroll
      for (int ni = 0; ni < 4; ++ni)
        acc[mi][ni] = __builtin_amdgcn_mfma_f32_16x16x32_bf16(
            a[mi], b[ni], acc[mi][ni], 0, 0, 0);
  }
  __syncthreads();  // all staging reads done before ctile aliasing write

  // ---- quantize: stage [row][col] in LDS + keep packed u64 per column ----
  unsigned mn = 0xFFFFu, mx = 0u;
  unsigned long long qp[4][4];
#pragma unroll
  for (int mi = 0; mi < 4; ++mi) {
#pragma unroll
    for (int ni = 0; ni < 4; ++ni) {
      int colL = wc * 64 + ni * 16 + l15;
      float ncol = norms[colBase + colL];
      unsigned long long pk = 0ull;
#pragma unroll
      for (int r = 0; r < 4; ++r) {
        int rowL = wr * 64 + mi * 16 + quad * 4 + r;
        int row = rowBase + rowL;
        float sq = norms[row] + ncol - 2.0f * acc[mi][ni][r];
        float d = sq > 0.f ? sqrtf(sq) : 0.f;
        if (row == colBase + colL) d = 0.f;
        unsigned q = (unsigned)(d * qscale);
        q = q > 65535u ? 65535u : q;
        ctile[rowL * PADW + colL] = (unsigned short)q;
        pk |= (unsigned long long)q << (16 * r);
        mx = max(mx, q);
        mn = min(mn, (row == colBase + colL) ? 0xFFFFu : q);
      }
      qp[mi][ni] = pk;
    }
  }
  __syncthreads();

  // ---- pass A: upper tile, coalesced uint4 rows from ctile[row][col] ----
  {
    const unsigned* cw = (const unsigned*)ctile;  // word rows, stride 66
    int i0 = tid >> 4, k4 = (tid & 15) * 4;
#pragma unroll
    for (int s = 0; s < 8; ++s) {
      int i = s * 16 + i0;
      int wb = i * (PADW / 2) + k4;
      uint4 v;
      v.x = cw[wb + 0];
      v.y = cw[wb + 1];
      v.z = cw[wb + 2];
      v.w = cw[wb + 3];
      *(uint4*)(distq + (size_t)(rowBase + i) * N + colBase + (tid & 15) * 8) =
          v;
    }
  }

  // ---- pass B: mirror tile via transposed restage (off-diag only) ----
  if (by != bx) {
    __syncthreads();  // pass-A reads done before overwrite
#pragma unroll
    for (int mi = 0; mi < 4; ++mi)
#pragma unroll
      for (int ni = 0; ni < 4; ++ni) {
        int colL = wc * 64 + ni * 16 + l15;
        int rowL0 = wr * 64 + mi * 16 + quad * 4;
        *(unsigned long long*)&ctile[colL * PADW + rowL0] = qp[mi][ni];
      }
    __syncthreads();
    const unsigned* cw = (const unsigned*)ctile;
    int j0 = tid >> 4, k4 = (tid & 15) * 4;
#pragma unroll
    for (int s = 0; s < 8; ++s) {
      int j = s * 16 + j0;
      int wb = j * (PADW / 2) + k4;
      uint4 v;
      v.x = cw[wb + 0];
      v.y = cw[wb + 1];
      v.z = cw[wb + 2];
      v.w = cw[wb + 3];
      *(uint4*)(distq + (size_t)(colBase + j) * N + rowBase + (tid & 15) * 8) =
          v;
    }
  }

  // ---- block-level min/max reduce -> 2 device atomics per block ----
#pragma unroll
  for (int d = 32; d; d >>= 1) {
    mn = min(mn, (unsigned)__shfl_xor((int)mn, d, 64));
    mx = max(mx, (unsigned)__shfl_xor((int)mx, d, 64));
  }
  if (lane == 0) {
    mmx[wave] = mn;
    mmx[4 + wave] = mx;
  }
  __syncthreads();
  if (tid == 0) {
    unsigned bmn = min(min(mmx[0], mmx[1]), min(mmx[2], mmx[3]));
    unsigned bmx = max(max(mmx[4], mmx[5]), max(mmx[6], mmx[7]));
    atomicMin(&qstats[ST_MIN + slot], bmn);
    atomicMax(&qstats[ST_MAX + slot], bmx);
  }
}

// ---------------- counting-based per-row ranks (4 rows / block) ----------
__device__ __forceinline__ int hsw(int w) { return w ^ ((w >> 5) & 31); }

__global__ __launch_bounds__(256) void rank_kernel(
    const unsigned short* __restrict__ qx,
    const unsigned short* __restrict__ qz,
    const unsigned* __restrict__ qstats,
    unsigned long long* __restrict__ rank_acc, double* __restrict__ pd_acc) {
  __shared__ unsigned histX[NWRD];  // 4 KB
  __shared__ unsigned histZ[NWRD];  // 4 KB
  __shared__ unsigned xch[32];

  int t = threadIdx.x, lane = t & 63, wv = t >> 6;
  int row0 = (int)blockIdx.x * RPB;

  float lox = (float)(int)qstats[ST_MIN + 0];
  float scx = (float)(NBIN - 1) /
              (float)(int)max(1u, qstats[ST_MAX + 0] - qstats[ST_MIN + 0]);
  float loz = (float)(int)qstats[ST_MIN + 1];
  float scz = (float)(NBIN - 1) /
              (float)(int)max(1u, qstats[ST_MAX + 1] - qstats[ST_MIN + 1]);

  const uint4* px = (const uint4*)(qx + (size_t)row0 * N);
  const uint4* pz = (const uint4*)(qz + (size_t)row0 * N);

  // preload row 0 of this block
  uint4 cxa = px[t * 2], cxb = px[t * 2 + 1];
  uint4 cza = pz[t * 2], czb = pz[t * 2 + 1];

  float pd = 0.f;
  int rsum = 0;

#pragma unroll 1
  for (int r = 0; r < RPB; ++r) {
    // zero hists
#pragma unroll
    for (int i = 0; i < 4; ++i) {
      histX[t + 256 * i] = 0u;
      histZ[t + 256 * i] = 0u;
    }
    // prefetch next row while this row's LDS phases run
    uint4 nxa = cxa, nxb = cxb, nza = cza, nzb = czb;
    if (r + 1 < RPB) {
      const uint4* npx = px + (size_t)(r + 1) * (N / 8);
      const uint4* npz = pz + (size_t)(r + 1) * (N / 8);
      nxa = npx[t * 2];
      nxb = npx[t * 2 + 1];
      nza = npz[t * 2];
      nzb = npz[t * 2 + 1];
    }

    unsigned xw[8] = {cxa.x, cxa.y, cxa.z, cxa.w, cxb.x, cxb.y, cxb.z, cxb.w};
    unsigned zw[8] = {cza.x, cza.y, cza.z, cza.w, czb.x, czb.y, czb.z, czb.w};

    // pairdist partial
#pragma unroll
    for (int c = 0; c < 16; ++c) {
      unsigned qxv = (xw[c >> 1] >> ((c & 1) * 16)) & 0xFFFFu;
      unsigned qzv = (zw[c >> 1] >> ((c & 1) * 16)) & 0xFFFFu;
      // dz-dx = ((qz+.5)/2048 - (qx+.5)/1024) = (qz - 2*qx - 0.5)/2048
      float tv = (float)(int)qzv - 2.0f * (float)(int)qxv - 0.5f;
      pd += tv * tv;
    }
    __syncthreads();  // hist zeroing complete

    // single atomic pass: count AND capture intra-bin offset
    unsigned oxp[8], ozp[8];
#pragma unroll
    for (int c = 0; c < 16; ++c) {
      unsigned qxv = (xw[c >> 1] >> ((c & 1) * 16)) & 0xFFFFu;
      unsigned qzv = (zw[c >> 1] >> ((c & 1) * 16)) & 0xFFFFu;
      unsigned bx = (unsigned)(int)fminf(
          fmaxf(((float)(int)qxv - lox) * scx, 0.0f), (float)(NBIN - 1));
      unsigned bz = (unsigned)(int)fminf(
          fmaxf(((float)(int)qzv - loz) * scz, 0.0f), (float)(NBIN - 1));
      unsigned shx = (bx & 1) * 16, shz = (bz & 1) * 16;
      unsigned ox =
          (atomicAdd(&histX[hsw((int)(bx >> 1))], 1u << shx) >> shx) & 0xFFFFu;
      unsigned oz =
          (atomicAdd(&histZ[hsw((int)(bz >> 1))], 1u << shz) >> shz) & 0xFFFFu;
      if (c & 1) {
        oxp[c >> 1] |= ox << 16;
        ozp[c >> 1] |= oz << 16;
      } else {
        oxp[c >> 1] = ox;
        ozp[c >> 1] = oz;
      }
    }
    __syncthreads();

    // dual exclusive scan: waves 0-1 -> histX, waves 2-3 -> histZ
    {
      unsigned* h = (wv < 2) ? histX : histZ;
      int t2 = t & 127;
      int wb = t2 * 8;
      unsigned run = 0;
#pragma unroll
      for (int c = 0; c < 8; ++c) {
        int w = hsw(wb + c);
        unsigned v = h[w];
        unsigned lo = v & 0xFFFFu;
        h[w] = run | ((run + lo) << 16);
        run += lo + (v >> 16);
      }
      unsigned incl = run;
#pragma unroll
      for (int d = 1; d < 64; d <<= 1) {
        unsigned o = (unsigned)__shfl_up((int)incl, d, 64);
        if (lane >= d) incl += o;
      }
      if (lane == 63) xch[16 + wv] = incl;
      __syncthreads();
      unsigned base = incl - run;              // exclusive within my wave
      if (wv & 1) base += xch[16 + (wv - 1)];  // add lower wave of my hist
      unsigned add = base * 0x10001u;
#pragma unroll
      for (int c = 0; c < 8; ++c) h[hsw(wb + c)] += add;
    }
    __syncthreads();

    // final pass: plain ds_read of scanned bases; |rx-rz| inline
#pragma unroll
    for (int c = 0; c < 16; ++c) {
      unsigned qxv = (xw[c >> 1] >> ((c & 1) * 16)) & 0xFFFFu;
      unsigned qzv = (zw[c >> 1] >> ((c & 1) * 16)) & 0xFFFFu;
      unsigned bx = (unsigned)(int)fminf(
          fmaxf(((float)(int)qxv - lox) * scx, 0.0f), (float)(NBIN - 1));
      unsigned bz = (unsigned)(int)fminf(
          fmaxf(((float)(int)qzv - loz) * scz, 0.0f), (float)(NBIN - 1));
      unsigned shx = (bx & 1) * 16, shz = (bz & 1) * 16;
      unsigned basex = (histX[hsw((int)(bx >> 1))] >> shx) & 0xFFFFu;
      unsigned basez = (histZ[hsw((int)(bz >> 1))] >> shz) & 0xFFFFu;
      int rx = (int)(basex + ((oxp[c >> 1] >> ((c & 1) * 16)) & 0xFFFFu));
      int rz = (int)(basez + ((ozp[c >> 1] >> ((c & 1) * 16)) & 0xFFFFu));
      int d = rx - rz;
      rsum += d < 0 ? -d : d;
    }
    __syncthreads();  // protect hist re-zero next iteration

    cxa = nxa;
    cxb = nxb;
    cza = nza;
    czb = nzb;
  }

  // block reduce + global atomics
#pragma unroll
  for (int d = 32; d; d >>= 1) {
    rsum += __shfl_xor(rsum, d, 64);
    pd += __shfl_xor(pd, d, 64);
  }
  if (lane == 0) {
    xch[wv] = (unsigned)rsum;
    ((float*)xch)[8 + wv] = pd;
  }
  __syncthreads();
  if (t == 0) {
    unsigned long long rtot =
        (unsigned long long)xch[0] + xch[1] + xch[2] + xch[3];
    float ptot = ((float*)xch)[8] + ((float*)xch)[9] + ((float*)xch)[10] +
                 ((float*)xch)[11];
    atomicAdd(rank_acc, rtot);
    atomicAdd(pd_acc, (double)ptot);
  }
}

// ---------------- finalize ----------------
__global__ void finalize_kernel(const unsigned long long* __restrict__ racc,
                                const double* __restrict__ pacc,
                                float* __restrict__ out) {
  double inv = 1.0 / ((double)N * (double)N);
  double rank_loss = (double)(*racc) * inv / 32.0;  // K = 32
  double pd = (*pacc) * inv / (2048.0 * 2048.0);    // undo q scaling
  out[0] = (float)(rank_loss + 0.5 * pd);
  out[1] = (float)rank_loss;
  out[2] = (float)pd;
}

// ---------------- launch ----------------
extern "C" void kernel_launch(void* const* d_in, const int* in_sizes, int n_in,
                              void* d_out, int out_size, void* d_ws,
                              size_t ws_size, hipStream_t stream) {
  (void)in_sizes; (void)n_in; (void)out_size; (void)ws_size;
  const float* x = (const float*)d_in[0];
  const float* z = (const float*)d_in[1];
  float* out = (float*)d_out;

  char* w = (char*)d_ws;
  unsigned short* qx16 = (unsigned short*)(w);             // 32 MB
  unsigned short* qz16 = (unsigned short*)(w + 33554432);  // 32 MB
  __hip_bfloat16* xb = (__hip_bfloat16*)(w + 67108864);    // 4 MB
  __hip_bfloat16* zb = (__hip_bfloat16*)(w + 71303168);    // 0.5 MB
  float* nx = (float*)(w + 71827456);
  float* nz = (float*)(w + 71843840);
  unsigned* qstats = (unsigned*)(w + 71860224);
  unsigned long long* rank_acc = (unsigned long long*)(w + 71860224);
  double* pd_acc = (double*)(w + 71860224 + 8);

  // [0..23] rank_acc, pd_acc, maxx, maxz -> 0 ; [24..31] minx, minz -> ~0
  (void)hipMemsetAsync(w + 71860224, 0, 24, stream);
  (void)hipMemsetAsync(w + 71860224 + 24, 0xFF, 8, stream);

  prep_kernel<<<N, 256, 0, stream>>>(x, z, xb, zb, nx, nz);

  gram_dist_kernel<<<NTRI, 256, 0, stream>>>(xb, nx, qx16, DX, 1024.0f,
                                             qstats, 0);
  gram_dist_kernel<<<NTRI, 256, 0, stream>>>(zb, nz, qz16, DZ, 2048.0f,
                                             qstats, 1);

  rank_kernel<<<N / RPB, 256, 0, stream>>>(qx16, qz16, qstats, rank_acc,
                                           pd_acc);

  finalize_kernel<<<1, 1, 0, stream>>>(rank_acc, pd_acc, out);
}

// Round 12
// 171.900 us; speedup vs baseline: 1.9623x; 1.0807x over previous
//
#include <hip/hip_runtime.h>
#include <hip/hip_bf16.h>

// Problem: N=4096, Dx=512, Dz=64.
// out[0]=total, out[1]=rank_loss, out[2]=pairdist_loss (f32).
//
// Pipeline:
//   1. prep: nx[i]=sum x[i]^2 (f32), nz likewise; cast x,z to bf16.
//   2. gram_both (ONE dispatch, 528 triangular blocks): each block runs the
//      full tile pipeline TWICE — z-tile (K=64) then x-tile (K=512). bf16
//      MFMA, dbuf global_load_lds staging, LDS-staged coalesced uint4 dist
//      writes, symmetric mirror via LDS transpose. q0=min(floor(d*qscale),
//      65535), qscale 1024 (x) / 2048 (z). min/max qstats: 2 atomics per
//      tile. Rationale: r11 showed gram_z (2 K-iters) costs ~as much as
//      gram_x (16 K-iters) — the ~45 us is common structure, so pay it once.
//   3. rank kernel: 1024 blocks x 256 thr, 4 rows/block, register
//      prefetch; global-normalized 11-bit bins; ds_add_rtn count+offset
//      pass; dual scan; plain ds_read final pass; |rx-rz| inline.
//   4. finalize: 3 scalars.

#define N 4096
#define DX 512
#define DZ 64
#define NBIN 2048
#define NWRD (NBIN / 2)
#define RPB 4

typedef __attribute__((ext_vector_type(8))) short short8;
typedef __attribute__((ext_vector_type(4))) float float4v;

// stats word layout (u32 index into qstats base):
//   [0..1] rank_acc (u64)  [2..3] pd_acc (double)
//   [4] maxx [5] maxz      [6] minx [7] minz
#define ST_MAX 4
#define ST_MIN 6

// ---------------- async 16B global -> LDS ----------------
__device__ __forceinline__ void async16(const void* g, void* l) {
  __builtin_amdgcn_global_load_lds(
      (const __attribute__((address_space(1))) unsigned int*)(g),
      (__attribute__((address_space(3))) unsigned int*)(l), 16, 0, 0);
}

// ---------------- prep: norms + bf16 casts ----------------
__global__ __launch_bounds__(256) void prep_kernel(
    const float* __restrict__ x, const float* __restrict__ z,
    __hip_bfloat16* __restrict__ xb, __hip_bfloat16* __restrict__ zb,
    float* __restrict__ nx, float* __restrict__ nz) {
  int row = blockIdx.x;
  int tid = threadIdx.x;
  __shared__ float red[256];

  float sx = 0.f;
  for (int c = tid; c < DX; c += 256) {
    float v = x[(size_t)row * DX + c];
    xb[(size_t)row * DX + c] = __float2bfloat16(v);
    sx += v * v;
  }
  red[tid] = sx;
  __syncthreads();
  for (int s = 128; s > 0; s >>= 1) {
    if (tid < s) red[tid] += red[tid + s];
    __syncthreads();
  }
  if (tid == 0) nx[row] = red[0];
  __syncthreads();

  float sz = 0.f;
  if (tid < DZ) {
    float v = z[(size_t)row * DZ + tid];
    zb[(size_t)row * DZ + tid] = __float2bfloat16(v);
    sz = v * v;
  }
  red[tid] = sz;
  __syncthreads();
  for (int s = 128; s > 0; s >>= 1) {
    if (tid < s) red[tid] += red[tid + s];
    __syncthreads();
  }
  if (tid == 0) nz[row] = red[0];
}

// ------- bf16 MFMA Gram tile pipeline (device fn, run per matrix) --------
#define TILE 128
#define BK 32
#define PADW 132  // ctile row stride in u16; 66 words (even -> 8B-aligned b64)
#define NT 32     // tiles per dimension
#define NTRI 528  // NT*(NT+1)/2

__device__ __forceinline__ void gram_tile(
    const __hip_bfloat16* __restrict__ Abf, const float* __restrict__ norms,
    unsigned short* __restrict__ distq, int K, float qscale,
    unsigned* __restrict__ qstats, int slot, int by, int bx, char* smem,
    unsigned* mmx) {
  unsigned short* ctile = (unsigned short*)smem;

  int tid = threadIdx.x;
  int wave = tid >> 6, lane = tid & 63;
  int wr = wave >> 1, wc = wave & 1;
  int quad = lane >> 4, l15 = lane & 15;

  int rowBase = by * TILE;
  int colBase = bx * TILE;

  float4v acc[4][4];
#pragma unroll
  for (int mi = 0; mi < 4; ++mi)
#pragma unroll
    for (int ni = 0; ni < 4; ++ni) {
      float4v zv = {0.f, 0.f, 0.f, 0.f};
      acc[mi][ni] = zv;
    }

  const char* Ab = (const char*)Abf;
  const size_t rb = (size_t)K * 2;  // row bytes
  int chunk0 = wave * 2, chunk1 = wave * 2 + 1;
  int rl = lane >> 2;        // row within a 16-row chunk (4 lanes/row)
  int cl = (lane & 3) * 16;  // byte col within 64B row

  // stage K-chunk kc into buffer b (byte-offset derived LDS pointers)
  auto stage = [&](int kc, int b) {
    const char* base = Ab + (size_t)kc * 2 + cl;
    short* sA = (short*)(smem + b * 16384);
    short* sB = (short*)(smem + b * 16384 + 8192);
    async16(base + (size_t)(rowBase + chunk0 * 16 + rl) * rb,
            &sA[chunk0 * 512]);
    async16(base + (size_t)(rowBase + chunk1 * 16 + rl) * rb,
            &sA[chunk1 * 512]);
    async16(base + (size_t)(colBase + chunk0 * 16 + rl) * rb,
            &sB[chunk0 * 512]);
    async16(base + (size_t)(colBase + chunk1 * 16 + rl) * rb,
            &sB[chunk1 * 512]);
  };

  stage(0, 0);  // preload first chunk
  int ib = 0;
  for (int kc = 0; kc < K; kc += BK, ib ^= 1) {
    __syncthreads();  // drains current buf's staging; prev readers done
    if (kc + BK < K) stage(kc + BK, ib ^ 1);  // in flight during MFMA

    const short* As = (const short*)(smem + ib * 16384);
    const short* Bs = (const short*)(smem + ib * 16384 + 8192);
    short8 a[4], b[4];
#pragma unroll
    for (int mi = 0; mi < 4; ++mi)
      a[mi] = *(const short8*)(&As[(wr * 64 + mi * 16 + l15) * BK + quad * 8]);
#pragma unroll
    for (int ni = 0; ni < 4; ++ni)
      b[ni] = *(const short8*)(&Bs[(wc * 64 + ni * 16 + l15) * BK + quad * 8]);
#pragma unroll
    for (int mi = 0; mi < 4; ++mi)
#pragma unroll
      for (int ni = 0; ni < 4; ++ni)
        acc[mi][ni] = __builtin_amdgcn_mfma_f32_16x16x32_bf16(
            a[mi], b[ni], acc[mi][ni], 0, 0, 0);
  }
  __syncthreads();  // all staging reads done before ctile aliasing write

  // ---- quantize: stage [row][col] in LDS + keep packed u64 per column ----
  unsigned mn = 0xFFFFu, mx = 0u;
  unsigned long long qp[4][4];
#pragma unroll
  for (int mi = 0; mi < 4; ++mi) {
#pragma unroll
    for (int ni = 0; ni < 4; ++ni) {
      int colL = wc * 64 + ni * 16 + l15;
      float ncol = norms[colBase + colL];
      unsigned long long pk = 0ull;
#pragma unroll
      for (int r = 0; r < 4; ++r) {
        int rowL = wr * 64 + mi * 16 + quad * 4 + r;
        int row = rowBase + rowL;
        float sq = norms[row] + ncol - 2.0f * acc[mi][ni][r];
        float d = sq > 0.f ? sqrtf(sq) : 0.f;
        if (row == colBase + colL) d = 0.f;
        unsigned q = (unsigned)(d * qscale);
        q = q > 65535u ? 65535u : q;
        ctile[rowL * PADW + colL] = (unsigned short)q;
        pk |= (unsigned long long)q << (16 * r);
        mx = max(mx, q);
        mn = min(mn, (row == colBase + colL) ? 0xFFFFu : q);
      }
      qp[mi][ni] = pk;
    }
  }
  __syncthreads();

  // ---- pass A: upper tile, coalesced uint4 rows from ctile[row][col] ----
  {
    const unsigned* cw = (const unsigned*)ctile;  // word rows, stride 66
    int i0 = tid >> 4, k4 = (tid & 15) * 4;
#pragma unroll
    for (int s = 0; s < 8; ++s) {
      int i = s * 16 + i0;
      int wb = i * (PADW / 2) + k4;
      uint4 v;
      v.x = cw[wb + 0];
      v.y = cw[wb + 1];
      v.z = cw[wb + 2];
      v.w = cw[wb + 3];
      *(uint4*)(distq + (size_t)(rowBase + i) * N + colBase + (tid & 15) * 8) =
          v;
    }
  }

  // ---- pass B: mirror tile via transposed restage (off-diag only) ----
  if (by != bx) {
    __syncthreads();  // pass-A reads done before overwrite
#pragma unroll
    for (int mi = 0; mi < 4; ++mi)
#pragma unroll
      for (int ni = 0; ni < 4; ++ni) {
        int colL = wc * 64 + ni * 16 + l15;
        int rowL0 = wr * 64 + mi * 16 + quad * 4;
        *(unsigned long long*)&ctile[colL * PADW + rowL0] = qp[mi][ni];
      }
    __syncthreads();
    const unsigned* cw = (const unsigned*)ctile;
    int j0 = tid >> 4, k4 = (tid & 15) * 4;
#pragma unroll
    for (int s = 0; s < 8; ++s) {
      int j = s * 16 + j0;
      int wb = j * (PADW / 2) + k4;
      uint4 v;
      v.x = cw[wb + 0];
      v.y = cw[wb + 1];
      v.z = cw[wb + 2];
      v.w = cw[wb + 3];
      *(uint4*)(distq + (size_t)(colBase + j) * N + rowBase + (tid & 15) * 8) =
          v;
    }
  }

  // ---- block-level min/max reduce -> 2 device atomics per tile ----
#pragma unroll
  for (int d = 32; d; d >>= 1) {
    mn = min(mn, (unsigned)__shfl_xor((int)mn, d, 64));
    mx = max(mx, (unsigned)__shfl_xor((int)mx, d, 64));
  }
  __syncthreads();  // pass B LDS reads done; mmx reuse safe
  if (lane == 0) {
    mmx[wave] = mn;
    mmx[4 + wave] = mx;
  }
  __syncthreads();
  if (tid == 0) {
    unsigned bmn = min(min(mmx[0], mmx[1]), min(mmx[2], mmx[3]));
    unsigned bmx = max(max(mmx[4], mmx[5]), max(mmx[6], mmx[7]));
    atomicMin(&qstats[ST_MIN + slot], bmn);
    atomicMax(&qstats[ST_MAX + slot], bmx);
  }
}

__global__ __launch_bounds__(256) void gram_both_kernel(
    const __hip_bfloat16* __restrict__ xb, const __hip_bfloat16* __restrict__ zb,
    const float* __restrict__ nx, const float* __restrict__ nz,
    unsigned short* __restrict__ qx16, unsigned short* __restrict__ qz16,
    unsigned* __restrict__ qstats) {
  __shared__ alignas(16) char smem[TILE * PADW * 2];  // 33 KB
  __shared__ unsigned mmx[8];

  // compact upper-triangular decode: row-major rows by=0..31, len 32-by
  int idx = (int)blockIdx.x;
  int by = (int)((65.0f - sqrtf(4225.0f - 8.0f * (float)idx)) * 0.5f);
  while (((by + 1) * (65 - (by + 1))) / 2 <= idx) ++by;
  while ((by * (65 - by)) / 2 > idx) --by;
  int bx = by + (idx - (by * (65 - by)) / 2);

  // z tile first (cheap, K=64), then x tile (K=512): tail is x-only
  gram_tile(zb, nz, qz16, DZ, 2048.0f, qstats, 1, by, bx, smem, mmx);
  __syncthreads();
  gram_tile(xb, nx, qx16, DX, 1024.0f, qstats, 0, by, bx, smem, mmx);
}

// ---------------- counting-based per-row ranks (4 rows / block) ----------
__device__ __forceinline__ int hsw(int w) { return w ^ ((w >> 5) & 31); }

__global__ __launch_bounds__(256) void rank_kernel(
    const unsigned short* __restrict__ qx,
    const unsigned short* __restrict__ qz,
    const unsigned* __restrict__ qstats,
    unsigned long long* __restrict__ rank_acc, double* __restrict__ pd_acc) {
  __shared__ unsigned histX[NWRD];  // 4 KB
  __shared__ unsigned histZ[NWRD];  // 4 KB
  __shared__ unsigned xch[32];

  int t = threadIdx.x, lane = t & 63, wv = t >> 6;
  int row0 = (int)blockIdx.x * RPB;

  float lox = (float)(int)qstats[ST_MIN + 0];
  float scx = (float)(NBIN - 1) /
              (float)(int)max(1u, qstats[ST_MAX + 0] - qstats[ST_MIN + 0]);
  float loz = (float)(int)qstats[ST_MIN + 1];
  float scz = (float)(NBIN - 1) /
              (float)(int)max(1u, qstats[ST_MAX + 1] - qstats[ST_MIN + 1]);

  const uint4* px = (const uint4*)(qx + (size_t)row0 * N);
  const uint4* pz = (const uint4*)(qz + (size_t)row0 * N);

  // preload row 0 of this block
  uint4 cxa = px[t * 2], cxb = px[t * 2 + 1];
  uint4 cza = pz[t * 2], czb = pz[t * 2 + 1];

  float pd = 0.f;
  int rsum = 0;

#pragma unroll 1
  for (int r = 0; r < RPB; ++r) {
    // zero hists
#pragma unroll
    for (int i = 0; i < 4; ++i) {
      histX[t + 256 * i] = 0u;
      histZ[t + 256 * i] = 0u;
    }
    // prefetch next row while this row's LDS phases run
    uint4 nxa = cxa, nxb = cxb, nza = cza, nzb = czb;
    if (r + 1 < RPB) {
      const uint4* npx = px + (size_t)(r + 1) * (N / 8);
      const uint4* npz = pz + (size_t)(r + 1) * (N / 8);
      nxa = npx[t * 2];
      nxb = npx[t * 2 + 1];
      nza = npz[t * 2];
      nzb = npz[t * 2 + 1];
    }

    unsigned xw[8] = {cxa.x, cxa.y, cxa.z, cxa.w, cxb.x, cxb.y, cxb.z, cxb.w};
    unsigned zw[8] = {cza.x, cza.y, cza.z, cza.w, czb.x, czb.y, czb.z, czb.w};

    // pairdist partial
#pragma unroll
    for (int c = 0; c < 16; ++c) {
      unsigned qxv = (xw[c >> 1] >> ((c & 1) * 16)) & 0xFFFFu;
      unsigned qzv = (zw[c >> 1] >> ((c & 1) * 16)) & 0xFFFFu;
      // dz-dx = ((qz+.5)/2048 - (qx+.5)/1024) = (qz - 2*qx - 0.5)/2048
      float tv = (float)(int)qzv - 2.0f * (float)(int)qxv - 0.5f;
      pd += tv * tv;
    }
    __syncthreads();  // hist zeroing complete

    // single atomic pass: count AND capture intra-bin offset
    unsigned oxp[8], ozp[8];
#pragma unroll
    for (int c = 0; c < 16; ++c) {
      unsigned qxv = (xw[c >> 1] >> ((c & 1) * 16)) & 0xFFFFu;
      unsigned qzv = (zw[c >> 1] >> ((c & 1) * 16)) & 0xFFFFu;
      unsigned bx = (unsigned)(int)fminf(
          fmaxf(((float)(int)qxv - lox) * scx, 0.0f), (float)(NBIN - 1));
      unsigned bz = (unsigned)(int)fminf(
          fmaxf(((float)(int)qzv - loz) * scz, 0.0f), (float)(NBIN - 1));
      unsigned shx = (bx & 1) * 16, shz = (bz & 1) * 16;
      unsigned ox =
          (atomicAdd(&histX[hsw((int)(bx >> 1))], 1u << shx) >> shx) & 0xFFFFu;
      unsigned oz =
          (atomicAdd(&histZ[hsw((int)(bz >> 1))], 1u << shz) >> shz) & 0xFFFFu;
      if (c & 1) {
        oxp[c >> 1] |= ox << 16;
        ozp[c >> 1] |= oz << 16;
      } else {
        oxp[c >> 1] = ox;
        ozp[c >> 1] = oz;
      }
    }
    __syncthreads();

    // dual exclusive scan: waves 0-1 -> histX, waves 2-3 -> histZ
    {
      unsigned* h = (wv < 2) ? histX : histZ;
      int t2 = t & 127;
      int wb = t2 * 8;
      unsigned run = 0;
#pragma unroll
      for (int c = 0; c < 8; ++c) {
        int w = hsw(wb + c);
        unsigned v = h[w];
        unsigned lo = v & 0xFFFFu;
        h[w] = run | ((run + lo) << 16);
        run += lo + (v >> 16);
      }
      unsigned incl = run;
#pragma unroll
      for (int d = 1; d < 64; d <<= 1) {
        unsigned o = (unsigned)__shfl_up((int)incl, d, 64);
        if (lane >= d) incl += o;
      }
      if (lane == 63) xch[16 + wv] = incl;
      __syncthreads();
      unsigned base = incl - run;              // exclusive within my wave
      if (wv & 1) base += xch[16 + (wv - 1)];  // add lower wave of my hist
      unsigned add = base * 0x10001u;
#pragma unroll
      for (int c = 0; c < 8; ++c) h[hsw(wb + c)] += add;
    }
    __syncthreads();

    // final pass: plain ds_read of scanned bases; |rx-rz| inline
#pragma unroll
    for (int c = 0; c < 16; ++c) {
      unsigned qxv = (xw[c >> 1] >> ((c & 1) * 16)) & 0xFFFFu;
      unsigned qzv = (zw[c >> 1] >> ((c & 1) * 16)) & 0xFFFFu;
      unsigned bx = (unsigned)(int)fminf(
          fmaxf(((float)(int)qxv - lox) * scx, 0.0f), (float)(NBIN - 1));
      unsigned bz = (unsigned)(int)fminf(
          fmaxf(((float)(int)qzv - loz) * scz, 0.0f), (float)(NBIN - 1));
      unsigned shx = (bx & 1) * 16, shz = (bz & 1) * 16;
      unsigned basex = (histX[hsw((int)(bx >> 1))] >> shx) & 0xFFFFu;
      unsigned basez = (histZ[hsw((int)(bz >> 1))] >> shz) & 0xFFFFu;
      int rx = (int)(basex + ((oxp[c >> 1] >> ((c & 1) * 16)) & 0xFFFFu));
      int rz = (int)(basez + ((ozp[c >> 1] >> ((c & 1) * 16)) & 0xFFFFu));
      int d = rx - rz;
      rsum += d < 0 ? -d : d;
    }
    __syncthreads();  // protect hist re-zero next iteration

    cxa = nxa;
    cxb = nxb;
    cza = nza;
    czb = nzb;
  }

  // block reduce + global atomics
#pragma unroll
  for (int d = 32; d; d >>= 1) {
    rsum += __shfl_xor(rsum, d, 64);
    pd += __shfl_xor(pd, d, 64);
  }
  if (lane == 0) {
    xch[wv] = (unsigned)rsum;
    ((float*)xch)[8 + wv] = pd;
  }
  __syncthreads();
  if (t == 0) {
    unsigned long long rtot =
        (unsigned long long)xch[0] + xch[1] + xch[2] + xch[3];
    float ptot = ((float*)xch)[8] + ((float*)xch)[9] + ((float*)xch)[10] +
                 ((float*)xch)[11];
    atomicAdd(rank_acc, rtot);
    atomicAdd(pd_acc, (double)ptot);
  }
}

// ---------------- finalize ----------------
__global__ void finalize_kernel(const unsigned long long* __restrict__ racc,
                                const double* __restrict__ pacc,
                                float* __restrict__ out) {
  double inv = 1.0 / ((double)N * (double)N);
  double rank_loss = (double)(*racc) * inv / 32.0;  // K = 32
  double pd = (*pacc) * inv / (2048.0 * 2048.0);    // undo q scaling
  out[0] = (float)(rank_loss + 0.5 * pd);
  out[1] = (float)rank_loss;
  out[2] = (float)pd;
}

// ---------------- launch ----------------
extern "C" void kernel_launch(void* const* d_in, const int* in_sizes, int n_in,
                              void* d_out, int out_size, void* d_ws,
                              size_t ws_size, hipStream_t stream) {
  (void)in_sizes; (void)n_in; (void)out_size; (void)ws_size;
  const float* x = (const float*)d_in[0];
  const float* z = (const float*)d_in[1];
  float* out = (float*)d_out;

  char* w = (char*)d_ws;
  unsigned short* qx16 = (unsigned short*)(w);             // 32 MB
  unsigned short* qz16 = (unsigned short*)(w + 33554432);  // 32 MB
  __hip_bfloat16* xb = (__hip_bfloat16*)(w + 67108864);    // 4 MB
  __hip_bfloat16* zb = (__hip_bfloat16*)(w + 71303168);    // 0.5 MB
  float* nx = (float*)(w + 71827456);
  float* nz = (float*)(w + 71843840);
  unsigned* qstats = (unsigned*)(w + 71860224);
  unsigned long long* rank_acc = (unsigned long long*)(w + 71860224);
  double* pd_acc = (double*)(w + 71860224 + 8);

  // [0..23] rank_acc, pd_acc, maxx, maxz -> 0 ; [24..31] minx, minz -> ~0
  (void)hipMemsetAsync(w + 71860224, 0, 24, stream);
  (void)hipMemsetAsync(w + 71860224 + 24, 0xFF, 8, stream);

  prep_kernel<<<N, 256, 0, stream>>>(x, z, xb, zb, nx, nz);

  gram_both_kernel<<<NTRI, 256, 0, stream>>>(xb, zb, nx, nz, qx16, qz16,
                                             qstats);

  rank_kernel<<<N / RPB, 256, 0, stream>>>(qx16, qz16, qstats, rank_acc,
                                           pd_acc);

  finalize_kernel<<<1, 1, 0, stream>>>(rank_acc, pd_acc, out);
}